// Round 1
// 186.166 us; speedup vs baseline: 1.0286x; 1.0286x over previous
//
#include <hip/hip_runtime.h>
#include <hip/hip_bf16.h>

typedef __bf16 bf16_t;
typedef __bf16 bf16x4 __attribute__((ext_vector_type(4)));
typedef __bf16 bf16x8 __attribute__((ext_vector_type(8)));
typedef float  f32x4  __attribute__((ext_vector_type(4)));
typedef float  f32x8  __attribute__((ext_vector_type(8)));

#define EMBED 512
#define NH    8
#define HD    64
#define SEQ   2048
#define MTOT  8192
#define SCQ   0.18033688011112042f   // log2(e) / sqrt(64), folded into Q

__device__ __forceinline__ float gelu_f(float x) {
    return 0.5f * x * (1.0f + erff(x * 0.7071067811865475f));
}

__device__ __forceinline__ f32x4 mfma16(bf16x8 a, bf16x8 b, f32x4 c) {
    return __builtin_amdgcn_mfma_f32_16x16x32_bf16(a, b, c, 0, 0, 0);
}

// ---------------------------------------------------------------------------
// Pre-convert fp32 -> bf16: x (16 segments of 256K elems) + Wq/Wk/Wv.
// grid (64, 19), 256 thr, 16 elems/thr.
// ---------------------------------------------------------------------------
__global__ __launch_bounds__(256)
void convert_kernel(const float* __restrict__ x,  const float* __restrict__ Wq,
                    const float* __restrict__ Wk, const float* __restrict__ Wv,
                    bf16_t* __restrict__ xb, bf16_t* __restrict__ wb)
{
    const int y = blockIdx.y;
    const float* src; bf16_t* dst;
    if (y < 16)      { src = x + (size_t)y * 262144; dst = xb + (size_t)y * 262144; }
    else if (y == 16){ src = Wq; dst = wb; }
    else if (y == 17){ src = Wk; dst = wb + 262144; }
    else             { src = Wv; dst = wb + 524288; }
    const int base = (blockIdx.x * 256 + threadIdx.x) * 16;
    const f32x8 a = *(const f32x8*)(src + base);
    const f32x8 b = *(const f32x8*)(src + base + 8);
    *(bf16x8*)(dst + base)     = __builtin_convertvector(a, bf16x8);
    *(bf16x8*)(dst + base + 8) = __builtin_convertvector(b, bf16x8);
}

// ---------------------------------------------------------------------------
// GEMM + bias + GELU.  C[m][n] = gelu( sum_k X[m][k]*W[n][k] + bias[n] )
// X always bf16. MODE 0: W bf16 (3 matrices concat in Wb); Q out pre-scaled
// by SCQ to [B,H,S,D]; K to [B,H,S,D]; V transposed to [B,H,D,S] via
// vectorized bf16x4 stores. MODE 1: W fp32 (Wo), fp32 [M,EMBED] out.
// 128 x NTILE tile, BK=64, 4 waves; register prefetch of next k-tile.
// Padded LDS stride 72 (<=2-way bank conflicts = free).
// ---------------------------------------------------------------------------
template<int MODE, int NTILE>
__global__ __launch_bounds__(256, 3)
void gemm_gelu_kernel(const bf16_t* __restrict__ Xb,
                      const bf16_t* __restrict__ Wb,   // MODE 0
                      const float*  __restrict__ Wf,   // MODE 1
                      const float*  __restrict__ Bq, const float* __restrict__ Bk,
                      const float*  __restrict__ Bv,
                      bf16_t* __restrict__ O0, bf16_t* __restrict__ O1,
                      bf16_t* __restrict__ O2, float* __restrict__ Of)
{
    constexpr int NTN = NTILE / 32;   // nt tiles per wave == B-staging iters/thr
    __shared__ __align__(16) bf16_t As[128 * 72];
    __shared__ __align__(16) bf16_t Bs[NTILE * 72];
    const int tid  = threadIdx.x;
    const int lane = tid & 63, w = tid >> 6, quad = lane >> 4, l15 = lane & 15;
    const int m0 = blockIdx.x * 128;
    int mat, n0;
    if (MODE == 0) { mat = blockIdx.y >> 2; n0 = (blockIdx.y & 3) * NTILE; }
    else           { mat = 0;               n0 = blockIdx.y * NTILE; }
    const bf16_t* W  = (MODE == 0) ? (Wb + (size_t)mat * 262144) : nullptr;
    const float*  Bi = (MODE == 1) ? Bq : (mat == 0 ? Bq : (mat == 1 ? Bk : Bv));

    const int wr = (w >> 1) * 64;            // wave row offset
    const int wc = (w & 1) * (NTILE / 2);    // wave col offset

    const int srow = tid >> 3, scol = (tid & 7) * 8;

    f32x4 acc[4][NTN];
#pragma unroll
    for (int a = 0; a < 4; ++a)
#pragma unroll
        for (int b = 0; b < NTN; ++b) acc[a][b] = f32x4{0.f, 0.f, 0.f, 0.f};

    bf16x8 xp[4];
    bf16x8 wpb[NTN];
    f32x8  wpf[NTN];

    // prologue: tile 0 -> regs
#pragma unroll
    for (int it = 0; it < 4; ++it)
        xp[it] = *(const bf16x8*)(Xb + (size_t)(m0 + it * 32 + srow) * EMBED + scol);
#pragma unroll
    for (int it = 0; it < NTN; ++it) {
        const int r = it * 32 + srow;
        if (MODE == 0) wpb[it] = *(const bf16x8*)(W + (size_t)(n0 + r) * EMBED + scol);
        else           wpf[it] = *(const f32x8*)(Wf + (size_t)(n0 + r) * EMBED + scol);
    }

#pragma unroll 1
    for (int kt = 0; kt < 8; ++kt) {
        __syncthreads();
#pragma unroll
        for (int it = 0; it < 4; ++it)
            *(bf16x8*)(As + (it * 32 + srow) * 72 + scol) = xp[it];
#pragma unroll
        for (int it = 0; it < NTN; ++it) {
            const int r = it * 32 + srow;
            if (MODE == 0) *(bf16x8*)(Bs + r * 72 + scol) = wpb[it];
            else *(bf16x8*)(Bs + r * 72 + scol) = __builtin_convertvector(wpf[it], bf16x8);
        }
        if (kt < 7) {
            const int k1 = (kt + 1) * 64;
#pragma unroll
            for (int it = 0; it < 4; ++it)
                xp[it] = *(const bf16x8*)(Xb + (size_t)(m0 + it * 32 + srow) * EMBED + k1 + scol);
#pragma unroll
            for (int it = 0; it < NTN; ++it) {
                const int r = it * 32 + srow;
                if (MODE == 0) wpb[it] = *(const bf16x8*)(W + (size_t)(n0 + r) * EMBED + k1 + scol);
                else           wpf[it] = *(const f32x8*)(Wf + (size_t)(n0 + r) * EMBED + k1 + scol);
            }
        }
        __syncthreads();
#pragma unroll
        for (int ks = 0; ks < 2; ++ks) {
            const int ko = (ks * 4 + quad) * 8;
            bf16x8 av[4], bv[NTN];
#pragma unroll
            for (int mt = 0; mt < 4; ++mt)
                av[mt] = *(const bf16x8*)(As + (wr + mt * 16 + l15) * 72 + ko);
#pragma unroll
            for (int nt = 0; nt < NTN; ++nt)
                bv[nt] = *(const bf16x8*)(Bs + (wc + nt * 16 + l15) * 72 + ko);
#pragma unroll
            for (int mt = 0; mt < 4; ++mt)
#pragma unroll
                for (int nt = 0; nt < NTN; ++nt)
                    acc[mt][nt] = mfma16(av[mt], bv[nt], acc[mt][nt]);
        }
    }

    // epilogue (C/D layout: col=l15, row=quad*4+i)
    float biasv[NTN];
#pragma unroll
    for (int nt = 0; nt < NTN; ++nt)
        biasv[nt] = Bi[n0 + wc + nt * 16 + l15];
#pragma unroll
    for (int mt = 0; mt < 4; ++mt) {
        const int mb = m0 + wr + mt * 16 + quad * 4;
        const int bb = mb >> 11, s0 = mb & (SEQ - 1);
#pragma unroll
        for (int nt = 0; nt < NTN; ++nt) {
            const int fc = n0 + wc + nt * 16 + l15;
            const int h = fc >> 6, d = fc & 63;
            float vv[4];
#pragma unroll
            for (int i = 0; i < 4; ++i) vv[i] = gelu_f(acc[mt][nt][i] + biasv[nt]);
            if (MODE == 1) {
#pragma unroll
                for (int i = 0; i < 4; ++i) Of[(size_t)(mb + i) * EMBED + fc] = vv[i];
            } else if (mat == 0) {
#pragma unroll
                for (int i = 0; i < 4; ++i)
                    O0[(((size_t)(bb * NH + h)) * SEQ + s0 + i) * HD + d] = (bf16_t)(vv[i] * SCQ);
            } else if (mat == 1) {
#pragma unroll
                for (int i = 0; i < 4; ++i)
                    O1[(((size_t)(bb * NH + h)) * SEQ + s0 + i) * HD + d] = (bf16_t)vv[i];
            } else {
                bf16x4 pk;
#pragma unroll
                for (int i = 0; i < 4; ++i) pk[i] = (bf16_t)vv[i];
                *(bf16x4*)(O2 + ((size_t)(bb * NH + h) * HD + d) * SEQ + s0) = pk;
            }
        }
    }
}

// ---------------------------------------------------------------------------
// Flash attention, S-transposed, fixed-shift softmax (no online max).
// Q pre-scaled by log2(e)/8 at projection => S is base-2; p = exp2(s - 8).
// Exact-math identical to softmax (shift cancels in p/sum(p)); scores here
// are O(1) so fp32 range is safe by >30 orders of magnitude.
// Block = 64 Q rows (4 waves x 16), KV tile 64 double-buffered, grid 32x32.
//
// LDS: UNPADDED stride 64 + XOR bank swizzle (elem col ^= (row&7)<<3, i.e.
// byte ^= (row&7)<<4). Total = 2*64*64*2*2 (K,V dbuf) + 4*16*64*2 (P)
// = 40960 B = exactly 160KiB/4 -> 4 blocks/CU (was 46080 -> 3 blocks/CU,
// and grid 1024 = 4/CU forced a 3+1 round split: measured Occupancy 24%).
// All LDS access patterns verified bank-even under the swizzle.
// s_setprio(1) around MFMA clusters (guide m191: +4-7% attn w/ independent
// blocks per CU). lsum kept as f32x4 (4 indep add chains), reduced at end.
// ---------------------------------------------------------------------------
__global__ __launch_bounds__(256, 4)
void flash_attn_kernel(const bf16_t* __restrict__ Q,
                       const bf16_t* __restrict__ K,
                       const bf16_t* __restrict__ Vt,
                       bf16_t* __restrict__ Og)
{
    __shared__ __align__(16) bf16_t Ks[2][64 * 64];
    __shared__ __align__(16) bf16_t Vs[2][64 * 64];
    __shared__ __align__(16) bf16_t Ps[4][16 * 64];

    const int tid  = threadIdx.x;
    const int lane = tid & 63, w = tid >> 6, quad = lane >> 4, l15 = lane & 15;
    const int bh = blockIdx.y;
    const int q0 = blockIdx.x * 64;
    const size_t baseQK = (size_t)bh * SEQ * HD;
    const size_t baseV  = (size_t)bh * HD * SEQ;
    const int wm = w * 16;
    const int cx = (l15 & 7) << 3;   // compute-side swizzle: rows read are ==l15 (mod 8)

    // Q as B-operand fragments: n=qrow=l15, k=ks*32+quad*8
    bf16x8 qf[2];
#pragma unroll
    for (int ks = 0; ks < 2; ++ks)
        qf[ks] = *(const bf16x8*)(Q + baseQK + (size_t)(q0 + wm + l15) * HD + ks * 32 + quad * 8);

    f32x4 lacc = f32x4{0.f, 0.f, 0.f, 0.f};
    f32x4 oacc[4];
#pragma unroll
    for (int nt = 0; nt < 4; ++nt) oacc[nt] = f32x4{0.f, 0.f, 0.f, 0.f};

    bf16_t* Pw = Ps[w];
    const int r0 = tid >> 3, c0 = (tid & 7) * 8;
    // staging offset, swizzled; rows r0 and r0+32 share (row&7) -> +2048
    const int sA = (r0 << 6) + (c0 ^ ((r0 & 7) << 3));
    bf16x8 kr0, kr1, vr0, vr1;

    // prologue: tile 0 -> buf0; tile 1 -> regs
    kr0 = *(const bf16x8*)(K + baseQK + (size_t)r0 * HD + c0);
    kr1 = *(const bf16x8*)(K + baseQK + (size_t)(r0 + 32) * HD + c0);
    vr0 = *(const bf16x8*)(Vt + baseV + (size_t)r0 * SEQ + c0);
    vr1 = *(const bf16x8*)(Vt + baseV + (size_t)(r0 + 32) * SEQ + c0);
    *(bf16x8*)(Ks[0] + sA)        = kr0;
    *(bf16x8*)(Ks[0] + sA + 2048) = kr1;
    *(bf16x8*)(Vs[0] + sA)        = vr0;
    *(bf16x8*)(Vs[0] + sA + 2048) = vr1;
    kr0 = *(const bf16x8*)(K + baseQK + (size_t)(64 + r0) * HD + c0);
    kr1 = *(const bf16x8*)(K + baseQK + (size_t)(64 + r0 + 32) * HD + c0);
    vr0 = *(const bf16x8*)(Vt + baseV + (size_t)r0 * SEQ + 64 + c0);
    vr1 = *(const bf16x8*)(Vt + baseV + (size_t)(r0 + 32) * SEQ + 64 + c0);

#pragma unroll 1
    for (int t = 0; t < 32; ++t) {
        __syncthreads();
        if (t + 1 < 32) {
            bf16_t* Kn = Ks[(t + 1) & 1];
            bf16_t* Vn = Vs[(t + 1) & 1];
            *(bf16x8*)(Kn + sA)        = kr0;
            *(bf16x8*)(Kn + sA + 2048) = kr1;
            *(bf16x8*)(Vn + sA)        = vr0;
            *(bf16x8*)(Vn + sA + 2048) = vr1;
        }
        if (t + 2 < 32) {
            const int kv = (t + 2) * 64;
            kr0 = *(const bf16x8*)(K + baseQK + (size_t)(kv + r0) * HD + c0);
            kr1 = *(const bf16x8*)(K + baseQK + (size_t)(kv + r0 + 32) * HD + c0);
            vr0 = *(const bf16x8*)(Vt + baseV + (size_t)r0 * SEQ + kv + c0);
            vr1 = *(const bf16x8*)(Vt + baseV + (size_t)(r0 + 32) * SEQ + kv + c0);
        }

        const bf16_t* Kb = Ks[t & 1];
        const bf16_t* Vb = Vs[t & 1];

        // S^T = K Q^T : lane holds S[qrow=l15][key=jt*16+quad*4+i] (base-2)
        f32x4 sf[4];
#pragma unroll
        for (int jt = 0; jt < 4; ++jt) sf[jt] = f32x4{0.f, 0.f, 0.f, 0.f};
        __builtin_amdgcn_s_setprio(1);
#pragma unroll
        for (int ks = 0; ks < 2; ++ks) {
            const int ko = (ks * 32 + quad * 8) ^ cx;
#pragma unroll
            for (int jt = 0; jt < 4; ++jt) {
                const bf16x8 a = *(const bf16x8*)(Kb + ((jt * 16 + l15) << 6) + ko);
                sf[jt] = mfma16(a, qf[ks], sf[jt]);
            }
        }
        __builtin_amdgcn_s_setprio(0);

        // fixed-shift exp: p = exp2(s - 8); accumulate 4 indep partial sums
#pragma unroll
        for (int jt = 0; jt < 4; ++jt) {
#pragma unroll
            for (int i = 0; i < 4; ++i) sf[jt][i] = exp2f(sf[jt][i] - 8.f);
            lacc += sf[jt];
            const bf16x4 pk = __builtin_convertvector(sf[jt], bf16x4);
            *(bf16x4*)(Pw + (l15 << 6) + ((jt * 16 + quad * 4) ^ cx)) = pk;
        }

        // O += P V : A = P (rows l15), B = Vt rows (d); 2 k-chunks of 32
        __builtin_amdgcn_s_setprio(1);
#pragma unroll
        for (int c = 0; c < 2; ++c) {
            const int ko = (c * 32 + quad * 8) ^ cx;
            const bf16x8 a = *(const bf16x8*)(Pw + (l15 << 6) + ko);
#pragma unroll
            for (int nt = 0; nt < 4; ++nt) {
                const bf16x8 b = *(const bf16x8*)(Vb + ((nt * 16 + l15) << 6) + ko);
                oacc[nt] = mfma16(a, b, oacc[nt]);
            }
        }
        __builtin_amdgcn_s_setprio(0);
    }

    // final l per qrow: reduce lane partials across quads, gather per C-row
    float rs = (lacc[0] + lacc[1]) + (lacc[2] + lacc[3]);
    rs += __shfl_xor(rs, 16);
    rs += __shfl_xor(rs, 32);
    const int bidx = bh >> 3, h = bh & 7;
    float lf[4];
#pragma unroll
    for (int i = 0; i < 4; ++i)
        lf[i] = __shfl(rs, (lane & 48) | (quad * 4 + i));
#pragma unroll
    for (int nt = 0; nt < 4; ++nt)
#pragma unroll
        for (int i = 0; i < 4; ++i) {
            const int s = q0 + wm + quad * 4 + i;
            const int d = nt * 16 + l15;
            Og[((size_t)(bidx * SEQ + s)) * EMBED + h * HD + d] =
                (bf16_t)(oacc[nt][i] / lf[i]);
        }
}

extern "C" void kernel_launch(void* const* d_in, const int* in_sizes, int n_in,
                              void* d_out, int out_size, void* d_ws, size_t ws_size,
                              hipStream_t stream)
{
    const float* x  = (const float*)d_in[0];
    const float* Wq = (const float*)d_in[1];
    const float* bq = (const float*)d_in[2];
    const float* Wk = (const float*)d_in[3];
    const float* bk = (const float*)d_in[4];
    const float* Wv = (const float*)d_in[5];
    const float* bv = (const float*)d_in[6];
    const float* Wo = (const float*)d_in[7];
    const float* bo = (const float*)d_in[8];
    float* out = (float*)d_out;

    const size_t NE = (size_t)MTOT * EMBED;   // 4,194,304 elems
    // Layout (ws use stays at proven 24 MB):
    //   d_out[0..NE)    : xb  (bf16 x)          -- dead after QKV GEMM
    //   d_out[NE..2NE)  : Qw  (bf16, pre-scaled)-- dead after flash
    //   ws[0..NE)       : Kw    ws[NE..2NE) : Vtw
    //   ws[2NE..3NE)    : Wb (1.5 MB, dead after QKV GEMM) then Ow (flash out)
    bf16_t* xb  = (bf16_t*)d_out;
    bf16_t* Qw  = (bf16_t*)d_out + NE;
    bf16_t* Kw  = (bf16_t*)d_ws;
    bf16_t* Vtw = Kw + NE;
    bf16_t* Ow  = Vtw + NE;
    bf16_t* Wb  = Ow;

    convert_kernel<<<dim3(64, 19), 256, 0, stream>>>(x, Wq, Wk, Wv, xb, Wb);
    gemm_gelu_kernel<0, 128><<<dim3(64, 12), 256, 0, stream>>>(
        xb, Wb, nullptr, bq, bk, bv, Qw, Kw, Vtw, nullptr);
    flash_attn_kernel<<<dim3(32, 32), 256, 0, stream>>>(Qw, Kw, Vtw, Ow);
    gemm_gelu_kernel<1, 64><<<dim3(64, 8), 256, 0, stream>>>(
        Ow, nullptr, Wo, bo, nullptr, nullptr, nullptr, nullptr, nullptr, out);
}

// Round 2
// 185.260 us; speedup vs baseline: 1.0337x; 1.0049x over previous
//
#include <hip/hip_runtime.h>
#include <hip/hip_bf16.h>

typedef __bf16 bf16_t;
typedef __bf16 bf16x4 __attribute__((ext_vector_type(4)));
typedef __bf16 bf16x8 __attribute__((ext_vector_type(8)));
typedef float  f32x4  __attribute__((ext_vector_type(4)));
typedef float  f32x8  __attribute__((ext_vector_type(8)));

#define EMBED 512
#define NH    8
#define HD    64
#define SEQ   2048
#define MTOT  8192
#define SCQ   0.18033688011112042f   // log2(e) / sqrt(64), folded into Q

__device__ __forceinline__ float gelu_f(float x) {
    return 0.5f * x * (1.0f + erff(x * 0.7071067811865475f));
}

__device__ __forceinline__ f32x4 mfma16(bf16x8 a, bf16x8 b, f32x4 c) {
    return __builtin_amdgcn_mfma_f32_16x16x32_bf16(a, b, c, 0, 0, 0);
}

// ---------------------------------------------------------------------------
// Pre-convert fp32 -> bf16: x (16 segments of 256K elems) + Wq/Wk/Wv.
// grid (64, 19), 256 thr, 16 elems/thr.
// ---------------------------------------------------------------------------
__global__ __launch_bounds__(256)
void convert_kernel(const float* __restrict__ x,  const float* __restrict__ Wq,
                    const float* __restrict__ Wk, const float* __restrict__ Wv,
                    bf16_t* __restrict__ xb, bf16_t* __restrict__ wb)
{
    const int y = blockIdx.y;
    const float* src; bf16_t* dst;
    if (y < 16)      { src = x + (size_t)y * 262144; dst = xb + (size_t)y * 262144; }
    else if (y == 16){ src = Wq; dst = wb; }
    else if (y == 17){ src = Wk; dst = wb + 262144; }
    else             { src = Wv; dst = wb + 524288; }
    const int base = (blockIdx.x * 256 + threadIdx.x) * 16;
    const f32x8 a = *(const f32x8*)(src + base);
    const f32x8 b = *(const f32x8*)(src + base + 8);
    *(bf16x8*)(dst + base)     = __builtin_convertvector(a, bf16x8);
    *(bf16x8*)(dst + base + 8) = __builtin_convertvector(b, bf16x8);
}

// ---------------------------------------------------------------------------
// GEMM + bias + GELU.  C[m][n] = gelu( sum_k X[m][k]*W[n][k] + bias[n] )
// X always bf16. MODE 0: W bf16 (3 matrices concat in Wb); Q out pre-scaled
// by SCQ to [B,H,S,D]; K to [B,H,S,D]; V transposed to [B,H,D,S] via
// vectorized bf16x4 stores. MODE 1: W fp32 (Wo), fp32 [M,EMBED] out.
// 128 x NTILE tile, BK=64, 4 waves; register prefetch of next k-tile.
// Padded LDS stride 72 (<=2-way bank conflicts = free).
// ---------------------------------------------------------------------------
template<int MODE, int NTILE>
__global__ __launch_bounds__(256, 3)
void gemm_gelu_kernel(const bf16_t* __restrict__ Xb,
                      const bf16_t* __restrict__ Wb,   // MODE 0
                      const float*  __restrict__ Wf,   // MODE 1
                      const float*  __restrict__ Bq, const float* __restrict__ Bk,
                      const float*  __restrict__ Bv,
                      bf16_t* __restrict__ O0, bf16_t* __restrict__ O1,
                      bf16_t* __restrict__ O2, float* __restrict__ Of)
{
    constexpr int NTN = NTILE / 32;   // nt tiles per wave == B-staging iters/thr
    __shared__ __align__(16) bf16_t As[128 * 72];
    __shared__ __align__(16) bf16_t Bs[NTILE * 72];
    const int tid  = threadIdx.x;
    const int lane = tid & 63, w = tid >> 6, quad = lane >> 4, l15 = lane & 15;
    const int m0 = blockIdx.x * 128;
    int mat, n0;
    if (MODE == 0) { mat = blockIdx.y >> 2; n0 = (blockIdx.y & 3) * NTILE; }
    else           { mat = 0;               n0 = blockIdx.y * NTILE; }
    const bf16_t* W  = (MODE == 0) ? (Wb + (size_t)mat * 262144) : nullptr;
    const float*  Bi = (MODE == 1) ? Bq : (mat == 0 ? Bq : (mat == 1 ? Bk : Bv));

    const int wr = (w >> 1) * 64;            // wave row offset
    const int wc = (w & 1) * (NTILE / 2);    // wave col offset

    const int srow = tid >> 3, scol = (tid & 7) * 8;

    f32x4 acc[4][NTN];
#pragma unroll
    for (int a = 0; a < 4; ++a)
#pragma unroll
        for (int b = 0; b < NTN; ++b) acc[a][b] = f32x4{0.f, 0.f, 0.f, 0.f};

    bf16x8 xp[4];
    bf16x8 wpb[NTN];
    f32x8  wpf[NTN];

    // prologue: tile 0 -> regs
#pragma unroll
    for (int it = 0; it < 4; ++it)
        xp[it] = *(const bf16x8*)(Xb + (size_t)(m0 + it * 32 + srow) * EMBED + scol);
#pragma unroll
    for (int it = 0; it < NTN; ++it) {
        const int r = it * 32 + srow;
        if (MODE == 0) wpb[it] = *(const bf16x8*)(W + (size_t)(n0 + r) * EMBED + scol);
        else           wpf[it] = *(const f32x8*)(Wf + (size_t)(n0 + r) * EMBED + scol);
    }

#pragma unroll 1
    for (int kt = 0; kt < 8; ++kt) {
        __syncthreads();
#pragma unroll
        for (int it = 0; it < 4; ++it)
            *(bf16x8*)(As + (it * 32 + srow) * 72 + scol) = xp[it];
#pragma unroll
        for (int it = 0; it < NTN; ++it) {
            const int r = it * 32 + srow;
            if (MODE == 0) *(bf16x8*)(Bs + r * 72 + scol) = wpb[it];
            else *(bf16x8*)(Bs + r * 72 + scol) = __builtin_convertvector(wpf[it], bf16x8);
        }
        if (kt < 7) {
            const int k1 = (kt + 1) * 64;
#pragma unroll
            for (int it = 0; it < 4; ++it)
                xp[it] = *(const bf16x8*)(Xb + (size_t)(m0 + it * 32 + srow) * EMBED + k1 + scol);
#pragma unroll
            for (int it = 0; it < NTN; ++it) {
                const int r = it * 32 + srow;
                if (MODE == 0) wpb[it] = *(const bf16x8*)(W + (size_t)(n0 + r) * EMBED + k1 + scol);
                else           wpf[it] = *(const f32x8*)(Wf + (size_t)(n0 + r) * EMBED + k1 + scol);
            }
        }
        __syncthreads();
#pragma unroll
        for (int ks = 0; ks < 2; ++ks) {
            const int ko = (ks * 4 + quad) * 8;
            bf16x8 av[4], bv[NTN];
#pragma unroll
            for (int mt = 0; mt < 4; ++mt)
                av[mt] = *(const bf16x8*)(As + (wr + mt * 16 + l15) * 72 + ko);
#pragma unroll
            for (int nt = 0; nt < NTN; ++nt)
                bv[nt] = *(const bf16x8*)(Bs + (wc + nt * 16 + l15) * 72 + ko);
#pragma unroll
            for (int mt = 0; mt < 4; ++mt)
#pragma unroll
                for (int nt = 0; nt < NTN; ++nt)
                    acc[mt][nt] = mfma16(av[mt], bv[nt], acc[mt][nt]);
        }
    }

    // epilogue (C/D layout: col=l15, row=quad*4+i)
    float biasv[NTN];
#pragma unroll
    for (int nt = 0; nt < NTN; ++nt)
        biasv[nt] = Bi[n0 + wc + nt * 16 + l15];
#pragma unroll
    for (int mt = 0; mt < 4; ++mt) {
        const int mb = m0 + wr + mt * 16 + quad * 4;
        const int bb = mb >> 11, s0 = mb & (SEQ - 1);
#pragma unroll
        for (int nt = 0; nt < NTN; ++nt) {
            const int fc = n0 + wc + nt * 16 + l15;
            const int h = fc >> 6, d = fc & 63;
            float vv[4];
#pragma unroll
            for (int i = 0; i < 4; ++i) vv[i] = gelu_f(acc[mt][nt][i] + biasv[nt]);
            if (MODE == 1) {
#pragma unroll
                for (int i = 0; i < 4; ++i) Of[(size_t)(mb + i) * EMBED + fc] = vv[i];
            } else if (mat == 0) {
#pragma unroll
                for (int i = 0; i < 4; ++i)
                    O0[(((size_t)(bb * NH + h)) * SEQ + s0 + i) * HD + d] = (bf16_t)(vv[i] * SCQ);
            } else if (mat == 1) {
#pragma unroll
                for (int i = 0; i < 4; ++i)
                    O1[(((size_t)(bb * NH + h)) * SEQ + s0 + i) * HD + d] = (bf16_t)vv[i];
            } else {
                bf16x4 pk;
#pragma unroll
                for (int i = 0; i < 4; ++i) pk[i] = (bf16_t)vv[i];
                *(bf16x4*)(O2 + ((size_t)(bb * NH + h) * HD + d) * SEQ + s0) = pk;
            }
        }
    }
}

// ---------------------------------------------------------------------------
// Flash attention, S-transposed, fixed-shift softmax (no online max).
// Q pre-scaled by log2(e)/8 at projection => S is base-2; p = exp2(s - 8).
//
// R2: 32 Q rows per wave (two 16-row groups g=0,1), 128 Q rows per block.
// K- and V-fragment LDS reads are SHARED across both g groups (read once,
// feed two MFMAs) -> LDS reads/MFMA drop 1.125 -> 0.625, staging + global
// K/V traffic per FLOP halve. Grid 16x32 = 512 blocks (2/CU), LDS 48 KiB.
// LDS unpadded stride 64 + XOR swizzle (col ^= (row&7)<<3) — bank-even,
// verified R1 (conflicts 11.5M -> 2.1M).
// ---------------------------------------------------------------------------
__global__ __launch_bounds__(256, 2)
void flash_attn_kernel(const bf16_t* __restrict__ Q,
                       const bf16_t* __restrict__ K,
                       const bf16_t* __restrict__ Vt,
                       bf16_t* __restrict__ Og)
{
    __shared__ __align__(16) bf16_t Ks[2][64 * 64];
    __shared__ __align__(16) bf16_t Vs[2][64 * 64];
    __shared__ __align__(16) bf16_t Ps[4][2][16 * 64];

    const int tid  = threadIdx.x;
    const int lane = tid & 63, w = tid >> 6, quad = lane >> 4, l15 = lane & 15;
    const int bh = blockIdx.y;
    const int q0 = blockIdx.x * 128;
    const size_t baseQK = (size_t)bh * SEQ * HD;
    const size_t baseV  = (size_t)bh * HD * SEQ;
    const int wm = w * 32;
    const int cx = (l15 & 7) << 3;   // compute-side swizzle: rows read are ==l15 (mod 8)

    // Q as B-operand fragments: n=qrow=l15 (per group), k=ks*32+quad*8
    bf16x8 qf0[2], qf1[2];
#pragma unroll
    for (int ks = 0; ks < 2; ++ks) {
        qf0[ks] = *(const bf16x8*)(Q + baseQK + (size_t)(q0 + wm + l15) * HD + ks * 32 + quad * 8);
        qf1[ks] = *(const bf16x8*)(Q + baseQK + (size_t)(q0 + wm + 16 + l15) * HD + ks * 32 + quad * 8);
    }

    f32x4 lacc0 = f32x4{0.f, 0.f, 0.f, 0.f};
    f32x4 lacc1 = f32x4{0.f, 0.f, 0.f, 0.f};
    f32x4 oacc0[4], oacc1[4];
#pragma unroll
    for (int nt = 0; nt < 4; ++nt) {
        oacc0[nt] = f32x4{0.f, 0.f, 0.f, 0.f};
        oacc1[nt] = f32x4{0.f, 0.f, 0.f, 0.f};
    }

    bf16_t* Pw0 = Ps[w][0];
    bf16_t* Pw1 = Ps[w][1];
    const int r0 = tid >> 3, c0 = (tid & 7) * 8;
    // staging offset, swizzled; rows r0 and r0+32 share (row&7) -> +2048
    const int sA = (r0 << 6) + (c0 ^ ((r0 & 7) << 3));
    bf16x8 kr0, kr1, vr0, vr1;

    // prologue: tile 0 -> buf0; tile 1 -> regs
    kr0 = *(const bf16x8*)(K + baseQK + (size_t)r0 * HD + c0);
    kr1 = *(const bf16x8*)(K + baseQK + (size_t)(r0 + 32) * HD + c0);
    vr0 = *(const bf16x8*)(Vt + baseV + (size_t)r0 * SEQ + c0);
    vr1 = *(const bf16x8*)(Vt + baseV + (size_t)(r0 + 32) * SEQ + c0);
    *(bf16x8*)(Ks[0] + sA)        = kr0;
    *(bf16x8*)(Ks[0] + sA + 2048) = kr1;
    *(bf16x8*)(Vs[0] + sA)        = vr0;
    *(bf16x8*)(Vs[0] + sA + 2048) = vr1;
    kr0 = *(const bf16x8*)(K + baseQK + (size_t)(64 + r0) * HD + c0);
    kr1 = *(const bf16x8*)(K + baseQK + (size_t)(64 + r0 + 32) * HD + c0);
    vr0 = *(const bf16x8*)(Vt + baseV + (size_t)r0 * SEQ + 64 + c0);
    vr1 = *(const bf16x8*)(Vt + baseV + (size_t)(r0 + 32) * SEQ + 64 + c0);

#pragma unroll 1
    for (int t = 0; t < 32; ++t) {
        __syncthreads();
        if (t + 1 < 32) {
            bf16_t* Kn = Ks[(t + 1) & 1];
            bf16_t* Vn = Vs[(t + 1) & 1];
            *(bf16x8*)(Kn + sA)        = kr0;
            *(bf16x8*)(Kn + sA + 2048) = kr1;
            *(bf16x8*)(Vn + sA)        = vr0;
            *(bf16x8*)(Vn + sA + 2048) = vr1;
        }
        if (t + 2 < 32) {
            const int kv = (t + 2) * 64;
            kr0 = *(const bf16x8*)(K + baseQK + (size_t)(kv + r0) * HD + c0);
            kr1 = *(const bf16x8*)(K + baseQK + (size_t)(kv + r0 + 32) * HD + c0);
            vr0 = *(const bf16x8*)(Vt + baseV + (size_t)r0 * SEQ + kv + c0);
            vr1 = *(const bf16x8*)(Vt + baseV + (size_t)(r0 + 32) * SEQ + kv + c0);
        }

        const bf16_t* Kb = Ks[t & 1];
        const bf16_t* Vb = Vs[t & 1];

        // S^T = K Q^T : lane holds S[qrow=l15(+g*16)][key=jt*16+quad*4+i]
        // K-fragment reads shared across both q-groups.
        f32x4 sf0[4], sf1[4];
#pragma unroll
        for (int jt = 0; jt < 4; ++jt) {
            sf0[jt] = f32x4{0.f, 0.f, 0.f, 0.f};
            sf1[jt] = f32x4{0.f, 0.f, 0.f, 0.f};
        }
        __builtin_amdgcn_s_setprio(1);
#pragma unroll
        for (int ks = 0; ks < 2; ++ks) {
            const int ko = (ks * 32 + quad * 8) ^ cx;
#pragma unroll
            for (int jt = 0; jt < 4; ++jt) {
                const bf16x8 a = *(const bf16x8*)(Kb + ((jt * 16 + l15) << 6) + ko);
                sf0[jt] = mfma16(a, qf0[ks], sf0[jt]);
                sf1[jt] = mfma16(a, qf1[ks], sf1[jt]);
            }
        }
        __builtin_amdgcn_s_setprio(0);

        // fixed-shift exp: p = exp2(s - 8); accumulate indep partial sums
#pragma unroll
        for (int jt = 0; jt < 4; ++jt) {
#pragma unroll
            for (int i = 0; i < 4; ++i) sf0[jt][i] = exp2f(sf0[jt][i] - 8.f);
            lacc0 += sf0[jt];
            const bf16x4 pk = __builtin_convertvector(sf0[jt], bf16x4);
            *(bf16x4*)(Pw0 + (l15 << 6) + ((jt * 16 + quad * 4) ^ cx)) = pk;
        }
#pragma unroll
        for (int jt = 0; jt < 4; ++jt) {
#pragma unroll
            for (int i = 0; i < 4; ++i) sf1[jt][i] = exp2f(sf1[jt][i] - 8.f);
            lacc1 += sf1[jt];
            const bf16x4 pk = __builtin_convertvector(sf1[jt], bf16x4);
            *(bf16x4*)(Pw1 + (l15 << 6) + ((jt * 16 + quad * 4) ^ cx)) = pk;
        }

        // O += P V : V-fragment reads shared across both q-groups.
        __builtin_amdgcn_s_setprio(1);
#pragma unroll
        for (int c = 0; c < 2; ++c) {
            const int ko = (c * 32 + quad * 8) ^ cx;
            const bf16x8 pa0 = *(const bf16x8*)(Pw0 + (l15 << 6) + ko);
            const bf16x8 pa1 = *(const bf16x8*)(Pw1 + (l15 << 6) + ko);
#pragma unroll
            for (int nt = 0; nt < 4; ++nt) {
                const bf16x8 b = *(const bf16x8*)(Vb + ((nt * 16 + l15) << 6) + ko);
                oacc0[nt] = mfma16(pa0, b, oacc0[nt]);
                oacc1[nt] = mfma16(pa1, b, oacc1[nt]);
            }
        }
        __builtin_amdgcn_s_setprio(0);
    }

    // final l per qrow: reduce lane partials across quads, gather per C-row
    const int bidx = bh >> 3, h = bh & 7;
#pragma unroll
    for (int g = 0; g < 2; ++g) {
        const f32x4 la = g ? lacc1 : lacc0;
        const f32x4* oa = g ? oacc1 : oacc0;
        float rs = (la[0] + la[1]) + (la[2] + la[3]);
        rs += __shfl_xor(rs, 16);
        rs += __shfl_xor(rs, 32);
        float lf[4];
#pragma unroll
        for (int i = 0; i < 4; ++i)
            lf[i] = __shfl(rs, (lane & 48) | (quad * 4 + i));
#pragma unroll
        for (int nt = 0; nt < 4; ++nt)
#pragma unroll
            for (int i = 0; i < 4; ++i) {
                const int s = q0 + wm + g * 16 + quad * 4 + i;
                const int d = nt * 16 + l15;
                Og[((size_t)(bidx * SEQ + s)) * EMBED + h * HD + d] =
                    (bf16_t)(oa[nt][i] / lf[i]);
            }
    }
}

extern "C" void kernel_launch(void* const* d_in, const int* in_sizes, int n_in,
                              void* d_out, int out_size, void* d_ws, size_t ws_size,
                              hipStream_t stream)
{
    const float* x  = (const float*)d_in[0];
    const float* Wq = (const float*)d_in[1];
    const float* bq = (const float*)d_in[2];
    const float* Wk = (const float*)d_in[3];
    const float* bk = (const float*)d_in[4];
    const float* Wv = (const float*)d_in[5];
    const float* bv = (const float*)d_in[6];
    const float* Wo = (const float*)d_in[7];
    const float* bo = (const float*)d_in[8];
    float* out = (float*)d_out;

    const size_t NE = (size_t)MTOT * EMBED;   // 4,194,304 elems
    // Layout (ws use stays at proven 24 MB):
    //   d_out[0..NE)    : xb  (bf16 x)          -- dead after QKV GEMM
    //   d_out[NE..2NE)  : Qw  (bf16, pre-scaled)-- dead after flash
    //   ws[0..NE)       : Kw    ws[NE..2NE) : Vtw
    //   ws[2NE..3NE)    : Wb (1.5 MB, dead after QKV GEMM) then Ow (flash out)
    bf16_t* xb  = (bf16_t*)d_out;
    bf16_t* Qw  = (bf16_t*)d_out + NE;
    bf16_t* Kw  = (bf16_t*)d_ws;
    bf16_t* Vtw = Kw + NE;
    bf16_t* Ow  = Vtw + NE;
    bf16_t* Wb  = Ow;

    convert_kernel<<<dim3(64, 19), 256, 0, stream>>>(x, Wq, Wk, Wv, xb, Wb);
    gemm_gelu_kernel<0, 128><<<dim3(64, 12), 256, 0, stream>>>(
        xb, Wb, nullptr, bq, bk, bv, Qw, Kw, Vtw, nullptr);
    flash_attn_kernel<<<dim3(16, 32), 256, 0, stream>>>(Qw, Kw, Vtw, Ow);
    gemm_gelu_kernel<1, 64><<<dim3(64, 8), 256, 0, stream>>>(
        Ow, nullptr, Wo, bo, nullptr, nullptr, nullptr, nullptr, nullptr, out);
}

// Round 3
// 183.324 us; speedup vs baseline: 1.0446x; 1.0106x over previous
//
#include <hip/hip_runtime.h>
#include <hip/hip_bf16.h>

typedef __bf16 bf16_t;
typedef __bf16 bf16x4 __attribute__((ext_vector_type(4)));
typedef __bf16 bf16x8 __attribute__((ext_vector_type(8)));
typedef float  f32x4  __attribute__((ext_vector_type(4)));
typedef float  f32x8  __attribute__((ext_vector_type(8)));

#define EMBED 512
#define NH    8
#define HD    64
#define SEQ   2048
#define MTOT  8192
#define SCQ   0.18033688011112042f   // log2(e) / sqrt(64), folded into Q

__device__ __forceinline__ float gelu_f(float x) {
    return 0.5f * x * (1.0f + erff(x * 0.7071067811865475f));
}

__device__ __forceinline__ f32x4 mfma16(bf16x8 a, bf16x8 b, f32x4 c) {
    return __builtin_amdgcn_mfma_f32_16x16x32_bf16(a, b, c, 0, 0, 0);
}

// Raw barrier: LDS-write visibility only (lgkmcnt(0)), NO vmcnt drain —
// global prefetch loads stay in flight across the barrier (T4 counted-vmcnt
// mechanism; the compiler emits counted vmcnt waits at the dependent
// ds_write). Compiler-level memory fences on both sides stop reordering.
__device__ __forceinline__ void barrier_nodrain() {
    asm volatile("s_waitcnt lgkmcnt(0)" ::: "memory");
    __builtin_amdgcn_s_barrier();
    asm volatile("" ::: "memory");
}

// ---------------------------------------------------------------------------
// Pre-convert fp32 -> bf16: x (16 segments of 256K elems) + Wq/Wk/Wv.
// grid (64, 19), 256 thr, 16 elems/thr.
// ---------------------------------------------------------------------------
__global__ __launch_bounds__(256)
void convert_kernel(const float* __restrict__ x,  const float* __restrict__ Wq,
                    const float* __restrict__ Wk, const float* __restrict__ Wv,
                    bf16_t* __restrict__ xb, bf16_t* __restrict__ wb)
{
    const int y = blockIdx.y;
    const float* src; bf16_t* dst;
    if (y < 16)      { src = x + (size_t)y * 262144; dst = xb + (size_t)y * 262144; }
    else if (y == 16){ src = Wq; dst = wb; }
    else if (y == 17){ src = Wk; dst = wb + 262144; }
    else             { src = Wv; dst = wb + 524288; }
    const int base = (blockIdx.x * 256 + threadIdx.x) * 16;
    const f32x8 a = *(const f32x8*)(src + base);
    const f32x8 b = *(const f32x8*)(src + base + 8);
    *(bf16x8*)(dst + base)     = __builtin_convertvector(a, bf16x8);
    *(bf16x8*)(dst + base + 8) = __builtin_convertvector(b, bf16x8);
}

// ---------------------------------------------------------------------------
// GEMM + bias + GELU.  C[m][n] = gelu( sum_k X[m][k]*W[n][k] + bias[n] )
// X always bf16. MODE 0: W bf16 (3 matrices concat in Wb); Q out pre-scaled
// by SCQ to [B,H,S,D]; K to [B,H,S,D]; V transposed to [B,H,D,S] via
// vectorized bf16x4 stores. MODE 1: W fp32 (Wo), fp32 [M,EMBED] out.
// 128 x NTILE tile, BK=64, 4 waves; register prefetch of next k-tile.
// R3: raw barriers (no vmcnt drain) — prefetch loads span the barriers.
// ---------------------------------------------------------------------------
template<int MODE, int NTILE>
__global__ __launch_bounds__(256, 3)
void gemm_gelu_kernel(const bf16_t* __restrict__ Xb,
                      const bf16_t* __restrict__ Wb,   // MODE 0
                      const float*  __restrict__ Wf,   // MODE 1
                      const float*  __restrict__ Bq, const float* __restrict__ Bk,
                      const float*  __restrict__ Bv,
                      bf16_t* __restrict__ O0, bf16_t* __restrict__ O1,
                      bf16_t* __restrict__ O2, float* __restrict__ Of)
{
    constexpr int NTN = NTILE / 32;   // nt tiles per wave == B-staging iters/thr
    __shared__ __align__(16) bf16_t As[128 * 72];
    __shared__ __align__(16) bf16_t Bs[NTILE * 72];
    const int tid  = threadIdx.x;
    const int lane = tid & 63, w = tid >> 6, quad = lane >> 4, l15 = lane & 15;
    const int m0 = blockIdx.x * 128;
    int mat, n0;
    if (MODE == 0) { mat = blockIdx.y >> 2; n0 = (blockIdx.y & 3) * NTILE; }
    else           { mat = 0;               n0 = blockIdx.y * NTILE; }
    const bf16_t* W  = (MODE == 0) ? (Wb + (size_t)mat * 262144) : nullptr;
    const float*  Bi = (MODE == 1) ? Bq : (mat == 0 ? Bq : (mat == 1 ? Bk : Bv));

    const int wr = (w >> 1) * 64;            // wave row offset
    const int wc = (w & 1) * (NTILE / 2);    // wave col offset

    const int srow = tid >> 3, scol = (tid & 7) * 8;

    f32x4 acc[4][NTN];
#pragma unroll
    for (int a = 0; a < 4; ++a)
#pragma unroll
        for (int b = 0; b < NTN; ++b) acc[a][b] = f32x4{0.f, 0.f, 0.f, 0.f};

    bf16x8 xp[4];
    bf16x8 wpb[NTN];
    f32x8  wpf[NTN];

    // prologue: tile 0 -> regs
#pragma unroll
    for (int it = 0; it < 4; ++it)
        xp[it] = *(const bf16x8*)(Xb + (size_t)(m0 + it * 32 + srow) * EMBED + scol);
#pragma unroll
    for (int it = 0; it < NTN; ++it) {
        const int r = it * 32 + srow;
        if (MODE == 0) wpb[it] = *(const bf16x8*)(W + (size_t)(n0 + r) * EMBED + scol);
        else           wpf[it] = *(const f32x8*)(Wf + (size_t)(n0 + r) * EMBED + scol);
    }

#pragma unroll 1
    for (int kt = 0; kt < 8; ++kt) {
        barrier_nodrain();   // readers of As/Bs (iter kt-1) are done
#pragma unroll
        for (int it = 0; it < 4; ++it)
            *(bf16x8*)(As + (it * 32 + srow) * 72 + scol) = xp[it];
#pragma unroll
        for (int it = 0; it < NTN; ++it) {
            const int r = it * 32 + srow;
            if (MODE == 0) *(bf16x8*)(Bs + r * 72 + scol) = wpb[it];
            else *(bf16x8*)(Bs + r * 72 + scol) = __builtin_convertvector(wpf[it], bf16x8);
        }
        if (kt < 7) {
            const int k1 = (kt + 1) * 64;
#pragma unroll
            for (int it = 0; it < 4; ++it)
                xp[it] = *(const bf16x8*)(Xb + (size_t)(m0 + it * 32 + srow) * EMBED + k1 + scol);
#pragma unroll
            for (int it = 0; it < NTN; ++it) {
                const int r = it * 32 + srow;
                if (MODE == 0) wpb[it] = *(const bf16x8*)(W + (size_t)(n0 + r) * EMBED + k1 + scol);
                else           wpf[it] = *(const f32x8*)(Wf + (size_t)(n0 + r) * EMBED + k1 + scol);
            }
        }
        barrier_nodrain();   // As/Bs writes visible to all waves
#pragma unroll
        for (int ks = 0; ks < 2; ++ks) {
            const int ko = (ks * 4 + quad) * 8;
            bf16x8 av[4], bv[NTN];
#pragma unroll
            for (int mt = 0; mt < 4; ++mt)
                av[mt] = *(const bf16x8*)(As + (wr + mt * 16 + l15) * 72 + ko);
#pragma unroll
            for (int nt = 0; nt < NTN; ++nt)
                bv[nt] = *(const bf16x8*)(Bs + (wc + nt * 16 + l15) * 72 + ko);
#pragma unroll
            for (int mt = 0; mt < 4; ++mt)
#pragma unroll
                for (int nt = 0; nt < NTN; ++nt)
                    acc[mt][nt] = mfma16(av[mt], bv[nt], acc[mt][nt]);
        }
    }

    // epilogue (C/D layout: col=l15, row=quad*4+i)
    float biasv[NTN];
#pragma unroll
    for (int nt = 0; nt < NTN; ++nt)
        biasv[nt] = Bi[n0 + wc + nt * 16 + l15];
#pragma unroll
    for (int mt = 0; mt < 4; ++mt) {
        const int mb = m0 + wr + mt * 16 + quad * 4;
        const int bb = mb >> 11, s0 = mb & (SEQ - 1);
#pragma unroll
        for (int nt = 0; nt < NTN; ++nt) {
            const int fc = n0 + wc + nt * 16 + l15;
            const int h = fc >> 6, d = fc & 63;
            float vv[4];
#pragma unroll
            for (int i = 0; i < 4; ++i) vv[i] = gelu_f(acc[mt][nt][i] + biasv[nt]);
            if (MODE == 1) {
#pragma unroll
                for (int i = 0; i < 4; ++i) Of[(size_t)(mb + i) * EMBED + fc] = vv[i];
            } else if (mat == 0) {
#pragma unroll
                for (int i = 0; i < 4; ++i)
                    O0[(((size_t)(bb * NH + h)) * SEQ + s0 + i) * HD + d] = (bf16_t)(vv[i] * SCQ);
            } else if (mat == 1) {
#pragma unroll
                for (int i = 0; i < 4; ++i)
                    O1[(((size_t)(bb * NH + h)) * SEQ + s0 + i) * HD + d] = (bf16_t)vv[i];
            } else {
                bf16x4 pk;
#pragma unroll
                for (int i = 0; i < 4; ++i) pk[i] = (bf16_t)vv[i];
                *(bf16x4*)(O2 + ((size_t)(bb * NH + h) * HD + d) * SEQ + s0) = pk;
            }
        }
    }
}

// ---------------------------------------------------------------------------
// Flash attention, S-transposed, fixed-shift softmax (no online max).
// Q pre-scaled by log2(e)/8 at projection => S is base-2; p = exp2(s - 8).
//
// R3: raw barrier (no vmcnt drain) + 2-tile-deep register prefetch.
// Loads for tile T+3 are issued at iter T into the reg set just written to
// LDS; the only VMEM wait is the compiler's counted vmcnt at the ds_write,
// two full iterations after issue -> HBM/L3 latency fully hidden.
// Two named reg sets with compile-time parity (loop unrolled x2 via macro)
// to avoid runtime-indexed reg arrays (scratch, rule #20).
// 32 Q rows/wave (two 16-row groups); K/V frag LDS reads shared across
// groups. LDS 48 KiB, grid 16x32 = 512 blocks = 2/CU exactly.
// XOR swizzle (col ^= (row&7)<<3) verified R1 (conflicts 11.5M -> 2.1M).
// ---------------------------------------------------------------------------
#define FA_ITER(T, BUF, KR0, KR1, VR0, VR1)                                   \
    do {                                                                      \
        if ((T) + 1 < 32) {                                                   \
            bf16_t* Kn = Ks[(BUF) ^ 1];                                       \
            bf16_t* Vn = Vs[(BUF) ^ 1];                                       \
            *(bf16x8*)(Kn + sA)        = KR0;                                 \
            *(bf16x8*)(Kn + sA + 2048) = KR1;                                 \
            *(bf16x8*)(Vn + sA)        = VR0;                                 \
            *(bf16x8*)(Vn + sA + 2048) = VR1;                                 \
        }                                                                     \
        if ((T) + 3 < 32) {                                                   \
            const int kv = ((T) + 3) * 64;                                    \
            KR0 = *(const bf16x8*)(K + baseQK + (size_t)(kv + r0) * HD + c0); \
            KR1 = *(const bf16x8*)(K + baseQK + (size_t)(kv + r0 + 32) * HD + c0); \
            VR0 = *(const bf16x8*)(Vt + baseV + (size_t)r0 * SEQ + kv + c0);  \
            VR1 = *(const bf16x8*)(Vt + baseV + (size_t)(r0 + 32) * SEQ + kv + c0); \
        }                                                                     \
        const bf16_t* Kb = Ks[(BUF)];                                         \
        const bf16_t* Vb = Vs[(BUF)];                                         \
        f32x4 sf0[4], sf1[4];                                                 \
        _Pragma("unroll")                                                     \
        for (int jt = 0; jt < 4; ++jt) {                                      \
            sf0[jt] = f32x4{0.f, 0.f, 0.f, 0.f};                              \
            sf1[jt] = f32x4{0.f, 0.f, 0.f, 0.f};                              \
        }                                                                     \
        __builtin_amdgcn_s_setprio(1);                                        \
        _Pragma("unroll")                                                     \
        for (int ks = 0; ks < 2; ++ks) {                                      \
            const int ko = (ks * 32 + quad * 8) ^ cx;                         \
            _Pragma("unroll")                                                 \
            for (int jt = 0; jt < 4; ++jt) {                                  \
                const bf16x8 a = *(const bf16x8*)(Kb + ((jt * 16 + l15) << 6) + ko); \
                sf0[jt] = mfma16(a, qf0[ks], sf0[jt]);                        \
                sf1[jt] = mfma16(a, qf1[ks], sf1[jt]);                        \
            }                                                                 \
        }                                                                     \
        __builtin_amdgcn_s_setprio(0);                                        \
        _Pragma("unroll")                                                     \
        for (int jt = 0; jt < 4; ++jt) {                                      \
            _Pragma("unroll")                                                 \
            for (int i = 0; i < 4; ++i) sf0[jt][i] = exp2f(sf0[jt][i] - 8.f); \
            lacc0 += sf0[jt];                                                 \
            const bf16x4 pk = __builtin_convertvector(sf0[jt], bf16x4);       \
            *(bf16x4*)(Pw0 + (l15 << 6) + ((jt * 16 + quad * 4) ^ cx)) = pk;  \
        }                                                                     \
        _Pragma("unroll")                                                     \
        for (int jt = 0; jt < 4; ++jt) {                                      \
            _Pragma("unroll")                                                 \
            for (int i = 0; i < 4; ++i) sf1[jt][i] = exp2f(sf1[jt][i] - 8.f); \
            lacc1 += sf1[jt];                                                 \
            const bf16x4 pk = __builtin_convertvector(sf1[jt], bf16x4);       \
            *(bf16x4*)(Pw1 + (l15 << 6) + ((jt * 16 + quad * 4) ^ cx)) = pk;  \
        }                                                                     \
        __builtin_amdgcn_s_setprio(1);                                        \
        _Pragma("unroll")                                                     \
        for (int c = 0; c < 2; ++c) {                                         \
            const int ko = (c * 32 + quad * 8) ^ cx;                          \
            const bf16x8 pa0 = *(const bf16x8*)(Pw0 + (l15 << 6) + ko);       \
            const bf16x8 pa1 = *(const bf16x8*)(Pw1 + (l15 << 6) + ko);       \
            _Pragma("unroll")                                                 \
            for (int nt = 0; nt < 4; ++nt) {                                  \
                const bf16x8 b = *(const bf16x8*)(Vb + ((nt * 16 + l15) << 6) + ko); \
                oacc0[nt] = mfma16(pa0, b, oacc0[nt]);                        \
                oacc1[nt] = mfma16(pa1, b, oacc1[nt]);                        \
            }                                                                 \
        }                                                                     \
        __builtin_amdgcn_s_setprio(0);                                        \
        if ((T) < 31) barrier_nodrain();                                      \
    } while (0)

__global__ __launch_bounds__(256, 2)
void flash_attn_kernel(const bf16_t* __restrict__ Q,
                       const bf16_t* __restrict__ K,
                       const bf16_t* __restrict__ Vt,
                       bf16_t* __restrict__ Og)
{
    __shared__ __align__(16) bf16_t Ks[2][64 * 64];
    __shared__ __align__(16) bf16_t Vs[2][64 * 64];
    __shared__ __align__(16) bf16_t Ps[4][2][16 * 64];

    const int tid  = threadIdx.x;
    const int lane = tid & 63, w = tid >> 6, quad = lane >> 4, l15 = lane & 15;
    const int bh = blockIdx.y;
    const int q0 = blockIdx.x * 128;
    const size_t baseQK = (size_t)bh * SEQ * HD;
    const size_t baseV  = (size_t)bh * HD * SEQ;
    const int wm = w * 32;
    const int cx = (l15 & 7) << 3;   // compute-side swizzle: rows read are ==l15 (mod 8)

    // Q as B-operand fragments: n=qrow=l15 (per group), k=ks*32+quad*8
    bf16x8 qf0[2], qf1[2];
#pragma unroll
    for (int ks = 0; ks < 2; ++ks) {
        qf0[ks] = *(const bf16x8*)(Q + baseQK + (size_t)(q0 + wm + l15) * HD + ks * 32 + quad * 8);
        qf1[ks] = *(const bf16x8*)(Q + baseQK + (size_t)(q0 + wm + 16 + l15) * HD + ks * 32 + quad * 8);
    }

    f32x4 lacc0 = f32x4{0.f, 0.f, 0.f, 0.f};
    f32x4 lacc1 = f32x4{0.f, 0.f, 0.f, 0.f};
    f32x4 oacc0[4], oacc1[4];
#pragma unroll
    for (int nt = 0; nt < 4; ++nt) {
        oacc0[nt] = f32x4{0.f, 0.f, 0.f, 0.f};
        oacc1[nt] = f32x4{0.f, 0.f, 0.f, 0.f};
    }

    bf16_t* Pw0 = Ps[w][0];
    bf16_t* Pw1 = Ps[w][1];
    const int r0 = tid >> 3, c0 = (tid & 7) * 8;
    // staging offset, swizzled; rows r0 and r0+32 share (row&7) -> +2048
    const int sA = (r0 << 6) + (c0 ^ ((r0 & 7) << 3));

    // reg sets: set B (idx 1) written at even t, set A (idx 0) at odd t.
    bf16x8 kA0, kA1, vA0, vA1;
    bf16x8 kB0, kB1, vB0, vB1;

    // prologue: T0 -> buf0 (via set A temp); T1 -> set B; T2 -> set A
    kA0 = *(const bf16x8*)(K + baseQK + (size_t)r0 * HD + c0);
    kA1 = *(const bf16x8*)(K + baseQK + (size_t)(r0 + 32) * HD + c0);
    vA0 = *(const bf16x8*)(Vt + baseV + (size_t)r0 * SEQ + c0);
    vA1 = *(const bf16x8*)(Vt + baseV + (size_t)(r0 + 32) * SEQ + c0);
    *(bf16x8*)(Ks[0] + sA)        = kA0;
    *(bf16x8*)(Ks[0] + sA + 2048) = kA1;
    *(bf16x8*)(Vs[0] + sA)        = vA0;
    *(bf16x8*)(Vs[0] + sA + 2048) = vA1;
    kB0 = *(const bf16x8*)(K + baseQK + (size_t)(64 + r0) * HD + c0);
    kB1 = *(const bf16x8*)(K + baseQK + (size_t)(64 + r0 + 32) * HD + c0);
    vB0 = *(const bf16x8*)(Vt + baseV + (size_t)r0 * SEQ + 64 + c0);
    vB1 = *(const bf16x8*)(Vt + baseV + (size_t)(r0 + 32) * SEQ + 64 + c0);
    kA0 = *(const bf16x8*)(K + baseQK + (size_t)(128 + r0) * HD + c0);
    kA1 = *(const bf16x8*)(K + baseQK + (size_t)(128 + r0 + 32) * HD + c0);
    vA0 = *(const bf16x8*)(Vt + baseV + (size_t)r0 * SEQ + 128 + c0);
    vA1 = *(const bf16x8*)(Vt + baseV + (size_t)(r0 + 32) * SEQ + 128 + c0);
    barrier_nodrain();

#pragma unroll 1
    for (int tt = 0; tt < 32; tt += 2) {
        FA_ITER(tt,     0, kB0, kB1, vB0, vB1);   // even t: buf0 compute, write set B
        FA_ITER(tt + 1, 1, kA0, kA1, vA0, vA1);   // odd t:  buf1 compute, write set A
    }

    // final l per qrow: reduce lane partials across quads, gather per C-row
    const int bidx = bh >> 3, h = bh & 7;
#pragma unroll
    for (int g = 0; g < 2; ++g) {
        const f32x4 la = g ? lacc1 : lacc0;
        const f32x4* oa = g ? oacc1 : oacc0;
        float rs = (la[0] + la[1]) + (la[2] + la[3]);
        rs += __shfl_xor(rs, 16);
        rs += __shfl_xor(rs, 32);
        float lf[4];
#pragma unroll
        for (int i = 0; i < 4; ++i)
            lf[i] = __shfl(rs, (lane & 48) | (quad * 4 + i));
#pragma unroll
        for (int nt = 0; nt < 4; ++nt)
#pragma unroll
            for (int i = 0; i < 4; ++i) {
                const int s = q0 + wm + g * 16 + quad * 4 + i;
                const int d = nt * 16 + l15;
                Og[((size_t)(bidx * SEQ + s)) * EMBED + h * HD + d] =
                    (bf16_t)(oa[nt][i] / lf[i]);
            }
    }
}

extern "C" void kernel_launch(void* const* d_in, const int* in_sizes, int n_in,
                              void* d_out, int out_size, void* d_ws, size_t ws_size,
                              hipStream_t stream)
{
    const float* x  = (const float*)d_in[0];
    const float* Wq = (const float*)d_in[1];
    const float* bq = (const float*)d_in[2];
    const float* Wk = (const float*)d_in[3];
    const float* bk = (const float*)d_in[4];
    const float* Wv = (const float*)d_in[5];
    const float* bv = (const float*)d_in[6];
    const float* Wo = (const float*)d_in[7];
    const float* bo = (const float*)d_in[8];
    float* out = (float*)d_out;

    const size_t NE = (size_t)MTOT * EMBED;   // 4,194,304 elems
    // Layout (ws use stays at proven 24 MB):
    //   d_out[0..NE)    : xb  (bf16 x)          -- dead after QKV GEMM
    //   d_out[NE..2NE)  : Qw  (bf16, pre-scaled)-- dead after flash
    //   ws[0..NE)       : Kw    ws[NE..2NE) : Vtw
    //   ws[2NE..3NE)    : Wb (1.5 MB, dead after QKV GEMM) then Ow (flash out)
    bf16_t* xb  = (bf16_t*)d_out;
    bf16_t* Qw  = (bf16_t*)d_out + NE;
    bf16_t* Kw  = (bf16_t*)d_ws;
    bf16_t* Vtw = Kw + NE;
    bf16_t* Ow  = Vtw + NE;
    bf16_t* Wb  = Ow;

    convert_kernel<<<dim3(64, 19), 256, 0, stream>>>(x, Wq, Wk, Wv, xb, Wb);
    gemm_gelu_kernel<0, 128><<<dim3(64, 12), 256, 0, stream>>>(
        xb, Wb, nullptr, bq, bk, bv, Qw, Kw, Vtw, nullptr);
    flash_attn_kernel<<<dim3(16, 32), 256, 0, stream>>>(Qw, Kw, Vtw, Ow);
    gemm_gelu_kernel<1, 64><<<dim3(64, 8), 256, 0, stream>>>(
        Ow, nullptr, Wo, bo, nullptr, nullptr, nullptr, nullptr, nullptr, out);
}

// Round 4
// 179.677 us; speedup vs baseline: 1.0658x; 1.0203x over previous
//
#include <hip/hip_runtime.h>
#include <hip/hip_bf16.h>

typedef __bf16 bf16_t;
typedef __bf16 bf16x4 __attribute__((ext_vector_type(4)));
typedef __bf16 bf16x8 __attribute__((ext_vector_type(8)));
typedef float  f32x4  __attribute__((ext_vector_type(4)));
typedef float  f32x8  __attribute__((ext_vector_type(8)));

#define EMBED 512
#define NH    8
#define HD    64
#define SEQ   2048
#define MTOT  8192
#define SCQ   0.18033688011112042f   // log2(e) / sqrt(64), folded into Q

__device__ __forceinline__ float gelu_f(float x) {
    return 0.5f * x * (1.0f + erff(x * 0.7071067811865475f));
}

__device__ __forceinline__ f32x4 mfma16(bf16x8 a, bf16x8 b, f32x4 c) {
    return __builtin_amdgcn_mfma_f32_16x16x32_bf16(a, b, c, 0, 0, 0);
}

// Raw barrier: LDS-write visibility only (lgkmcnt(0)), NO vmcnt drain —
// global prefetch loads stay in flight across the barrier; the compiler
// emits counted vmcnt waits at the dependent ds_write.
__device__ __forceinline__ void barrier_nodrain() {
    asm volatile("s_waitcnt lgkmcnt(0)" ::: "memory");
    __builtin_amdgcn_s_barrier();
    asm volatile("" ::: "memory");
}

// ---------------------------------------------------------------------------
// Pre-convert fp32 -> bf16: x (16 segments of 256K elems) + Wq/Wk/Wv.
// grid (64, 19), 256 thr, 16 elems/thr.
// ---------------------------------------------------------------------------
__global__ __launch_bounds__(256)
void convert_kernel(const float* __restrict__ x,  const float* __restrict__ Wq,
                    const float* __restrict__ Wk, const float* __restrict__ Wv,
                    bf16_t* __restrict__ xb, bf16_t* __restrict__ wb)
{
    const int y = blockIdx.y;
    const float* src; bf16_t* dst;
    if (y < 16)      { src = x + (size_t)y * 262144; dst = xb + (size_t)y * 262144; }
    else if (y == 16){ src = Wq; dst = wb; }
    else if (y == 17){ src = Wk; dst = wb + 262144; }
    else             { src = Wv; dst = wb + 524288; }
    const int base = (blockIdx.x * 256 + threadIdx.x) * 16;
    const f32x8 a = *(const f32x8*)(src + base);
    const f32x8 b = *(const f32x8*)(src + base + 8);
    *(bf16x8*)(dst + base)     = __builtin_convertvector(a, bf16x8);
    *(bf16x8*)(dst + base + 8) = __builtin_convertvector(b, bf16x8);
}

// ---------------------------------------------------------------------------
// GEMM + bias + GELU.  C[m][n] = gelu( sum_k X[m][k]*W[n][k] + bias[n] )
// X always bf16. MODE 0: W bf16 (3 matrices concat in Wb); Q out pre-scaled
// by SCQ to [B,H,S,D]; K to [B,H,S,D]; V transposed to [B,H,D,S] via
// vectorized bf16x4 stores. MODE 1: W fp32 (Wo), fp32 [M,EMBED] out.
// 128 x NTILE tile, BK=64, 4 waves; register prefetch of next k-tile.
// Raw barriers (no vmcnt drain) — prefetch loads span the barriers.
// ---------------------------------------------------------------------------
template<int MODE, int NTILE>
__global__ __launch_bounds__(256, 3)
void gemm_gelu_kernel(const bf16_t* __restrict__ Xb,
                      const bf16_t* __restrict__ Wb,   // MODE 0
                      const float*  __restrict__ Wf,   // MODE 1
                      const float*  __restrict__ Bq, const float* __restrict__ Bk,
                      const float*  __restrict__ Bv,
                      bf16_t* __restrict__ O0, bf16_t* __restrict__ O1,
                      bf16_t* __restrict__ O2, float* __restrict__ Of)
{
    constexpr int NTN = NTILE / 32;   // nt tiles per wave == B-staging iters/thr
    __shared__ __align__(16) bf16_t As[128 * 72];
    __shared__ __align__(16) bf16_t Bs[NTILE * 72];
    const int tid  = threadIdx.x;
    const int lane = tid & 63, w = tid >> 6, quad = lane >> 4, l15 = lane & 15;
    const int m0 = blockIdx.x * 128;
    int mat, n0;
    if (MODE == 0) { mat = blockIdx.y >> 2; n0 = (blockIdx.y & 3) * NTILE; }
    else           { mat = 0;               n0 = blockIdx.y * NTILE; }
    const bf16_t* W  = (MODE == 0) ? (Wb + (size_t)mat * 262144) : nullptr;
    const float*  Bi = (MODE == 1) ? Bq : (mat == 0 ? Bq : (mat == 1 ? Bk : Bv));

    const int wr = (w >> 1) * 64;            // wave row offset
    const int wc = (w & 1) * (NTILE / 2);    // wave col offset

    const int srow = tid >> 3, scol = (tid & 7) * 8;

    f32x4 acc[4][NTN];
#pragma unroll
    for (int a = 0; a < 4; ++a)
#pragma unroll
        for (int b = 0; b < NTN; ++b) acc[a][b] = f32x4{0.f, 0.f, 0.f, 0.f};

    bf16x8 xp[4];
    bf16x8 wpb[NTN];
    f32x8  wpf[NTN];

    // prologue: tile 0 -> regs
#pragma unroll
    for (int it = 0; it < 4; ++it)
        xp[it] = *(const bf16x8*)(Xb + (size_t)(m0 + it * 32 + srow) * EMBED + scol);
#pragma unroll
    for (int it = 0; it < NTN; ++it) {
        const int r = it * 32 + srow;
        if (MODE == 0) wpb[it] = *(const bf16x8*)(W + (size_t)(n0 + r) * EMBED + scol);
        else           wpf[it] = *(const f32x8*)(Wf + (size_t)(n0 + r) * EMBED + scol);
    }

#pragma unroll 1
    for (int kt = 0; kt < 8; ++kt) {
        barrier_nodrain();   // readers of As/Bs (iter kt-1) are done
#pragma unroll
        for (int it = 0; it < 4; ++it)
            *(bf16x8*)(As + (it * 32 + srow) * 72 + scol) = xp[it];
#pragma unroll
        for (int it = 0; it < NTN; ++it) {
            const int r = it * 32 + srow;
            if (MODE == 0) *(bf16x8*)(Bs + r * 72 + scol) = wpb[it];
            else *(bf16x8*)(Bs + r * 72 + scol) = __builtin_convertvector(wpf[it], bf16x8);
        }
        if (kt < 7) {
            const int k1 = (kt + 1) * 64;
#pragma unroll
            for (int it = 0; it < 4; ++it)
                xp[it] = *(const bf16x8*)(Xb + (size_t)(m0 + it * 32 + srow) * EMBED + k1 + scol);
#pragma unroll
            for (int it = 0; it < NTN; ++it) {
                const int r = it * 32 + srow;
                if (MODE == 0) wpb[it] = *(const bf16x8*)(W + (size_t)(n0 + r) * EMBED + k1 + scol);
                else           wpf[it] = *(const f32x8*)(Wf + (size_t)(n0 + r) * EMBED + k1 + scol);
            }
        }
        barrier_nodrain();   // As/Bs writes visible to all waves
#pragma unroll
        for (int ks = 0; ks < 2; ++ks) {
            const int ko = (ks * 4 + quad) * 8;
            bf16x8 av[4], bv[NTN];
#pragma unroll
            for (int mt = 0; mt < 4; ++mt)
                av[mt] = *(const bf16x8*)(As + (wr + mt * 16 + l15) * 72 + ko);
#pragma unroll
            for (int nt = 0; nt < NTN; ++nt)
                bv[nt] = *(const bf16x8*)(Bs + (wc + nt * 16 + l15) * 72 + ko);
#pragma unroll
            for (int mt = 0; mt < 4; ++mt)
#pragma unroll
                for (int nt = 0; nt < NTN; ++nt)
                    acc[mt][nt] = mfma16(av[mt], bv[nt], acc[mt][nt]);
        }
    }

    // epilogue (C/D layout: col=l15, row=quad*4+i)
    float biasv[NTN];
#pragma unroll
    for (int nt = 0; nt < NTN; ++nt)
        biasv[nt] = Bi[n0 + wc + nt * 16 + l15];
#pragma unroll
    for (int mt = 0; mt < 4; ++mt) {
        const int mb = m0 + wr + mt * 16 + quad * 4;
        const int bb = mb >> 11, s0 = mb & (SEQ - 1);
#pragma unroll
        for (int nt = 0; nt < NTN; ++nt) {
            const int fc = n0 + wc + nt * 16 + l15;
            const int h = fc >> 6, d = fc & 63;
            float vv[4];
#pragma unroll
            for (int i = 0; i < 4; ++i) vv[i] = gelu_f(acc[mt][nt][i] + biasv[nt]);
            if (MODE == 1) {
#pragma unroll
                for (int i = 0; i < 4; ++i) Of[(size_t)(mb + i) * EMBED + fc] = vv[i];
            } else if (mat == 0) {
#pragma unroll
                for (int i = 0; i < 4; ++i)
                    O0[(((size_t)(bb * NH + h)) * SEQ + s0 + i) * HD + d] = (bf16_t)(vv[i] * SCQ);
            } else if (mat == 1) {
#pragma unroll
                for (int i = 0; i < 4; ++i)
                    O1[(((size_t)(bb * NH + h)) * SEQ + s0 + i) * HD + d] = (bf16_t)vv[i];
            } else {
                bf16x4 pk;
#pragma unroll
                for (int i = 0; i < 4; ++i) pk[i] = (bf16_t)vv[i];
                *(bf16x4*)(O2 + ((size_t)(bb * NH + h) * HD + d) * SEQ + s0) = pk;
            }
        }
    }
}

// ---------------------------------------------------------------------------
// Flash attention, S-transposed, scale-free softmax: p = exp2(s) directly
// (Q pre-scaled by log2(e)/8 at projection; any fixed shift cancels in
// p/sum(p), so no subtract at all — p ~ O(1), sums < 4K, fp32/bf16 safe).
//
// R4: BACK to 16 Q rows/wave (64/block), grid 32x32 = 1024 blocks.
// Rationale: total waves = Qrows/rows-per-wave; 32 rows/wave capped the
// machine at 2 waves/SIMD and R1-R3 A/Bs show the kernel is dependency-
// latency-bound (pipes ~50% idle with 2/SIMD). 16 rows/wave -> 4096 waves
// = 4/SIMD (50% occ cap), LDS 40KB = exactly 4 blocks/CU.
// KEPT from R3: no-drain barriers + 2-tile-deep A/B register prefetch
// (loads issued 3 tiles ahead, counted-vmcnt only at ds_write).
// KEPT from R1: XOR swizzle (col ^= (row&7)<<3), conflict-verified.
// ---------------------------------------------------------------------------
#define FA_ITER(T, BUF, KR0, KR1, VR0, VR1)                                   \
    do {                                                                      \
        if ((T) + 1 < 32) {                                                   \
            bf16_t* Kn = Ks[(BUF) ^ 1];                                       \
            bf16_t* Vn = Vs[(BUF) ^ 1];                                       \
            *(bf16x8*)(Kn + sA)        = KR0;                                 \
            *(bf16x8*)(Kn + sA + 2048) = KR1;                                 \
            *(bf16x8*)(Vn + sA)        = VR0;                                 \
            *(bf16x8*)(Vn + sA + 2048) = VR1;                                 \
        }                                                                     \
        if ((T) + 3 < 32) {                                                   \
            const int kv = ((T) + 3) * 64;                                    \
            KR0 = *(const bf16x8*)(K + baseQK + (size_t)(kv + r0) * HD + c0); \
            KR1 = *(const bf16x8*)(K + baseQK + (size_t)(kv + r0 + 32) * HD + c0); \
            VR0 = *(const bf16x8*)(Vt + baseV + (size_t)r0 * SEQ + kv + c0);  \
            VR1 = *(const bf16x8*)(Vt + baseV + (size_t)(r0 + 32) * SEQ + kv + c0); \
        }                                                                     \
        const bf16_t* Kb = Ks[(BUF)];                                         \
        const bf16_t* Vb = Vs[(BUF)];                                         \
        f32x4 sf[4];                                                          \
        _Pragma("unroll")                                                     \
        for (int jt = 0; jt < 4; ++jt) sf[jt] = f32x4{0.f, 0.f, 0.f, 0.f};    \
        __builtin_amdgcn_s_setprio(1);                                        \
        _Pragma("unroll")                                                     \
        for (int ks = 0; ks < 2; ++ks) {                                      \
            const int ko = (ks * 32 + quad * 8) ^ cx;                         \
            _Pragma("unroll")                                                 \
            for (int jt = 0; jt < 4; ++jt) {                                  \
                const bf16x8 a = *(const bf16x8*)(Kb + ((jt * 16 + l15) << 6) + ko); \
                sf[jt] = mfma16(a, qf[ks], sf[jt]);                           \
            }                                                                 \
        }                                                                     \
        __builtin_amdgcn_s_setprio(0);                                        \
        _Pragma("unroll")                                                     \
        for (int jt = 0; jt < 4; ++jt) {                                      \
            _Pragma("unroll")                                                 \
            for (int i = 0; i < 4; ++i) sf[jt][i] = exp2f(sf[jt][i]);         \
            lacc += sf[jt];                                                   \
            const bf16x4 pk = __builtin_convertvector(sf[jt], bf16x4);        \
            *(bf16x4*)(Pw + (l15 << 6) + ((jt * 16 + quad * 4) ^ cx)) = pk;   \
        }                                                                     \
        __builtin_amdgcn_s_setprio(1);                                        \
        _Pragma("unroll")                                                     \
        for (int c = 0; c < 2; ++c) {                                         \
            const int ko = (c * 32 + quad * 8) ^ cx;                          \
            const bf16x8 pa = *(const bf16x8*)(Pw + (l15 << 6) + ko);         \
            _Pragma("unroll")                                                 \
            for (int nt = 0; nt < 4; ++nt) {                                  \
                const bf16x8 b = *(const bf16x8*)(Vb + ((nt * 16 + l15) << 6) + ko); \
                oacc[nt] = mfma16(pa, b, oacc[nt]);                           \
            }                                                                 \
        }                                                                     \
        __builtin_amdgcn_s_setprio(0);                                        \
        if ((T) < 31) barrier_nodrain();                                      \
    } while (0)

__global__ __launch_bounds__(256, 4)
void flash_attn_kernel(const bf16_t* __restrict__ Q,
                       const bf16_t* __restrict__ K,
                       const bf16_t* __restrict__ Vt,
                       bf16_t* __restrict__ Og)
{
    __shared__ __align__(16) bf16_t Ks[2][64 * 64];
    __shared__ __align__(16) bf16_t Vs[2][64 * 64];
    __shared__ __align__(16) bf16_t Ps[4][16 * 64];

    const int tid  = threadIdx.x;
    const int lane = tid & 63, w = tid >> 6, quad = lane >> 4, l15 = lane & 15;
    const int bh = blockIdx.y;
    const int q0 = blockIdx.x * 64;
    const size_t baseQK = (size_t)bh * SEQ * HD;
    const size_t baseV  = (size_t)bh * HD * SEQ;
    const int wm = w * 16;
    const int cx = (l15 & 7) << 3;   // compute-side swizzle: rows read are ==l15 (mod 8)

    // Q as B-operand fragments: n=qrow=l15, k=ks*32+quad*8
    bf16x8 qf[2];
#pragma unroll
    for (int ks = 0; ks < 2; ++ks)
        qf[ks] = *(const bf16x8*)(Q + baseQK + (size_t)(q0 + wm + l15) * HD + ks * 32 + quad * 8);

    f32x4 lacc = f32x4{0.f, 0.f, 0.f, 0.f};
    f32x4 oacc[4];
#pragma unroll
    for (int nt = 0; nt < 4; ++nt) oacc[nt] = f32x4{0.f, 0.f, 0.f, 0.f};

    bf16_t* Pw = Ps[w];
    const int r0 = tid >> 3, c0 = (tid & 7) * 8;
    // staging offset, swizzled; rows r0 and r0+32 share (row&7) -> +2048
    const int sA = (r0 << 6) + (c0 ^ ((r0 & 7) << 3));

    // reg sets: set B (idx 1) written at even t, set A (idx 0) at odd t.
    bf16x8 kA0, kA1, vA0, vA1;
    bf16x8 kB0, kB1, vB0, vB1;

    // prologue: T0 -> buf0 (via set A temp); T1 -> set B; T2 -> set A
    kA0 = *(const bf16x8*)(K + baseQK + (size_t)r0 * HD + c0);
    kA1 = *(const bf16x8*)(K + baseQK + (size_t)(r0 + 32) * HD + c0);
    vA0 = *(const bf16x8*)(Vt + baseV + (size_t)r0 * SEQ + c0);
    vA1 = *(const bf16x8*)(Vt + baseV + (size_t)(r0 + 32) * SEQ + c0);
    *(bf16x8*)(Ks[0] + sA)        = kA0;
    *(bf16x8*)(Ks[0] + sA + 2048) = kA1;
    *(bf16x8*)(Vs[0] + sA)        = vA0;
    *(bf16x8*)(Vs[0] + sA + 2048) = vA1;
    kB0 = *(const bf16x8*)(K + baseQK + (size_t)(64 + r0) * HD + c0);
    kB1 = *(const bf16x8*)(K + baseQK + (size_t)(64 + r0 + 32) * HD + c0);
    vB0 = *(const bf16x8*)(Vt + baseV + (size_t)r0 * SEQ + 64 + c0);
    vB1 = *(const bf16x8*)(Vt + baseV + (size_t)(r0 + 32) * SEQ + 64 + c0);
    kA0 = *(const bf16x8*)(K + baseQK + (size_t)(128 + r0) * HD + c0);
    kA1 = *(const bf16x8*)(K + baseQK + (size_t)(128 + r0 + 32) * HD + c0);
    vA0 = *(const bf16x8*)(Vt + baseV + (size_t)r0 * SEQ + 128 + c0);
    vA1 = *(const bf16x8*)(Vt + baseV + (size_t)(r0 + 32) * SEQ + 128 + c0);
    barrier_nodrain();

#pragma unroll 1
    for (int tt = 0; tt < 32; tt += 2) {
        FA_ITER(tt,     0, kB0, kB1, vB0, vB1);   // even t: buf0 compute, write set B
        FA_ITER(tt + 1, 1, kA0, kA1, vA0, vA1);   // odd t:  buf1 compute, write set A
    }

    // final l per qrow: reduce lane partials across quads, gather per C-row
    const int bidx = bh >> 3, h = bh & 7;
    float rs = (lacc[0] + lacc[1]) + (lacc[2] + lacc[3]);
    rs += __shfl_xor(rs, 16);
    rs += __shfl_xor(rs, 32);
    float lf[4];
#pragma unroll
    for (int i = 0; i < 4; ++i)
        lf[i] = __shfl(rs, (lane & 48) | (quad * 4 + i));
#pragma unroll
    for (int nt = 0; nt < 4; ++nt)
#pragma unroll
        for (int i = 0; i < 4; ++i) {
            const int s = q0 + wm + quad * 4 + i;
            const int d = nt * 16 + l15;
            Og[((size_t)(bidx * SEQ + s)) * EMBED + h * HD + d] =
                (bf16_t)(oacc[nt][i] / lf[i]);
        }
}

extern "C" void kernel_launch(void* const* d_in, const int* in_sizes, int n_in,
                              void* d_out, int out_size, void* d_ws, size_t ws_size,
                              hipStream_t stream)
{
    const float* x  = (const float*)d_in[0];
    const float* Wq = (const float*)d_in[1];
    const float* bq = (const float*)d_in[2];
    const float* Wk = (const float*)d_in[3];
    const float* bk = (const float*)d_in[4];
    const float* Wv = (const float*)d_in[5];
    const float* bv = (const float*)d_in[6];
    const float* Wo = (const float*)d_in[7];
    const float* bo = (const float*)d_in[8];
    float* out = (float*)d_out;

    const size_t NE = (size_t)MTOT * EMBED;   // 4,194,304 elems
    // Layout (ws use stays at proven 24 MB):
    //   d_out[0..NE)    : xb  (bf16 x)          -- dead after QKV GEMM
    //   d_out[NE..2NE)  : Qw  (bf16, pre-scaled)-- dead after flash
    //   ws[0..NE)       : Kw    ws[NE..2NE) : Vtw
    //   ws[2NE..3NE)    : Wb (1.5 MB, dead after QKV GEMM) then Ow (flash out)
    bf16_t* xb  = (bf16_t*)d_out;
    bf16_t* Qw  = (bf16_t*)d_out + NE;
    bf16_t* Kw  = (bf16_t*)d_ws;
    bf16_t* Vtw = Kw + NE;
    bf16_t* Ow  = Vtw + NE;
    bf16_t* Wb  = Ow;

    convert_kernel<<<dim3(64, 19), 256, 0, stream>>>(x, Wq, Wk, Wv, xb, Wb);
    gemm_gelu_kernel<0, 128><<<dim3(64, 12), 256, 0, stream>>>(
        xb, Wb, nullptr, bq, bk, bv, Qw, Kw, Vtw, nullptr);
    flash_attn_kernel<<<dim3(32, 32), 256, 0, stream>>>(Qw, Kw, Vtw, Ow);
    gemm_gelu_kernel<1, 64><<<dim3(64, 8), 256, 0, stream>>>(
        Ow, nullptr, Wo, bo, nullptr, nullptr, nullptr, nullptr, nullptr, out);
}

// Round 5
// 179.144 us; speedup vs baseline: 1.0690x; 1.0030x over previous
//
#include <hip/hip_runtime.h>
#include <hip/hip_bf16.h>

typedef __bf16 bf16_t;
typedef __bf16 bf16x4 __attribute__((ext_vector_type(4)));
typedef __bf16 bf16x8 __attribute__((ext_vector_type(8)));
typedef float  f32x4  __attribute__((ext_vector_type(4)));
typedef float  f32x8  __attribute__((ext_vector_type(8)));
typedef unsigned int u32;
typedef u32 u32x4 __attribute__((ext_vector_type(4)));

#define EMBED 512
#define NH    8
#define HD    64
#define SEQ   2048
#define MTOT  8192
#define SCQ   0.18033688011112042f   // log2(e) / sqrt(64), folded into Q

__device__ __forceinline__ float gelu_f(float x) {
    return 0.5f * x * (1.0f + erff(x * 0.7071067811865475f));
}

__device__ __forceinline__ f32x4 mfma16(bf16x8 a, bf16x8 b, f32x4 c) {
    return __builtin_amdgcn_mfma_f32_16x16x32_bf16(a, b, c, 0, 0, 0);
}

// Raw barrier: LDS-write visibility only (lgkmcnt(0)), NO vmcnt drain —
// global prefetch loads stay in flight across the barrier; the compiler
// emits counted vmcnt waits at the dependent ds_write.
__device__ __forceinline__ void barrier_nodrain() {
    asm volatile("s_waitcnt lgkmcnt(0)" ::: "memory");
    __builtin_amdgcn_s_barrier();
    asm volatile("" ::: "memory");
}

// T12 primitives: pack 2 f32 -> 1 u32 of 2 bf16 (RNE, same as convertvector),
// and the gfx950 cross-lane register swaps (pure VALU — no LDS pipe).
__device__ __forceinline__ u32 cvtpk_bf16(float lo, float hi) {
    u32 r;
    asm("v_cvt_pk_bf16_f32 %0, %1, %2" : "=v"(r) : "v"(lo), "v"(hi));
    return r;
}
__device__ __forceinline__ void swap32(u32& a, u32& b) {
    asm volatile("v_permlane32_swap_b32 %0, %1" : "+v"(a), "+v"(b));
}
__device__ __forceinline__ void swap16(u32& a, u32& b) {
    asm volatile("v_permlane16_swap_b32 %0, %1" : "+v"(a), "+v"(b));
}

// ---------------------------------------------------------------------------
// Pre-convert fp32 -> bf16: x (16 segments of 256K elems) + Wq/Wk/Wv.
// grid (64, 19), 256 thr, 16 elems/thr.
// ---------------------------------------------------------------------------
__global__ __launch_bounds__(256)
void convert_kernel(const float* __restrict__ x,  const float* __restrict__ Wq,
                    const float* __restrict__ Wk, const float* __restrict__ Wv,
                    bf16_t* __restrict__ xb, bf16_t* __restrict__ wb)
{
    const int y = blockIdx.y;
    const float* src; bf16_t* dst;
    if (y < 16)      { src = x + (size_t)y * 262144; dst = xb + (size_t)y * 262144; }
    else if (y == 16){ src = Wq; dst = wb; }
    else if (y == 17){ src = Wk; dst = wb + 262144; }
    else             { src = Wv; dst = wb + 524288; }
    const int base = (blockIdx.x * 256 + threadIdx.x) * 16;
    const f32x8 a = *(const f32x8*)(src + base);
    const f32x8 b = *(const f32x8*)(src + base + 8);
    *(bf16x8*)(dst + base)     = __builtin_convertvector(a, bf16x8);
    *(bf16x8*)(dst + base + 8) = __builtin_convertvector(b, bf16x8);
}

// ---------------------------------------------------------------------------
// GEMM + bias + GELU.  C[m][n] = gelu( sum_k X[m][k]*W[n][k] + bias[n] )
// X always bf16. MODE 0: W bf16 (3 matrices concat in Wb); Q out pre-scaled
// by SCQ to [B,H,S,D]; K to [B,H,S,D]; V transposed to [B,H,D,S] via
// vectorized bf16x4 stores. MODE 1: W fp32 (Wo), fp32 [M,EMBED] out.
// 128 x NTILE tile, BK=64, 4 waves; register prefetch of next k-tile.
// Raw barriers (no vmcnt drain) — prefetch loads span the barriers.
// ---------------------------------------------------------------------------
template<int MODE, int NTILE>
__global__ __launch_bounds__(256, 3)
void gemm_gelu_kernel(const bf16_t* __restrict__ Xb,
                      const bf16_t* __restrict__ Wb,   // MODE 0
                      const float*  __restrict__ Wf,   // MODE 1
                      const float*  __restrict__ Bq, const float* __restrict__ Bk,
                      const float*  __restrict__ Bv,
                      bf16_t* __restrict__ O0, bf16_t* __restrict__ O1,
                      bf16_t* __restrict__ O2, float* __restrict__ Of)
{
    constexpr int NTN = NTILE / 32;   // nt tiles per wave == B-staging iters/thr
    __shared__ __align__(16) bf16_t As[128 * 72];
    __shared__ __align__(16) bf16_t Bs[NTILE * 72];
    const int tid  = threadIdx.x;
    const int lane = tid & 63, w = tid >> 6, quad = lane >> 4, l15 = lane & 15;
    const int m0 = blockIdx.x * 128;
    int mat, n0;
    if (MODE == 0) { mat = blockIdx.y >> 2; n0 = (blockIdx.y & 3) * NTILE; }
    else           { mat = 0;               n0 = blockIdx.y * NTILE; }
    const bf16_t* W  = (MODE == 0) ? (Wb + (size_t)mat * 262144) : nullptr;
    const float*  Bi = (MODE == 1) ? Bq : (mat == 0 ? Bq : (mat == 1 ? Bk : Bv));

    const int wr = (w >> 1) * 64;            // wave row offset
    const int wc = (w & 1) * (NTILE / 2);    // wave col offset

    const int srow = tid >> 3, scol = (tid & 7) * 8;

    f32x4 acc[4][NTN];
#pragma unroll
    for (int a = 0; a < 4; ++a)
#pragma unroll
        for (int b = 0; b < NTN; ++b) acc[a][b] = f32x4{0.f, 0.f, 0.f, 0.f};

    bf16x8 xp[4];
    bf16x8 wpb[NTN];
    f32x8  wpf[NTN];

    // prologue: tile 0 -> regs
#pragma unroll
    for (int it = 0; it < 4; ++it)
        xp[it] = *(const bf16x8*)(Xb + (size_t)(m0 + it * 32 + srow) * EMBED + scol);
#pragma unroll
    for (int it = 0; it < NTN; ++it) {
        const int r = it * 32 + srow;
        if (MODE == 0) wpb[it] = *(const bf16x8*)(W + (size_t)(n0 + r) * EMBED + scol);
        else           wpf[it] = *(const f32x8*)(Wf + (size_t)(n0 + r) * EMBED + scol);
    }

#pragma unroll 1
    for (int kt = 0; kt < 8; ++kt) {
        barrier_nodrain();   // readers of As/Bs (iter kt-1) are done
#pragma unroll
        for (int it = 0; it < 4; ++it)
            *(bf16x8*)(As + (it * 32 + srow) * 72 + scol) = xp[it];
#pragma unroll
        for (int it = 0; it < NTN; ++it) {
            const int r = it * 32 + srow;
            if (MODE == 0) *(bf16x8*)(Bs + r * 72 + scol) = wpb[it];
            else *(bf16x8*)(Bs + r * 72 + scol) = __builtin_convertvector(wpf[it], bf16x8);
        }
        if (kt < 7) {
            const int k1 = (kt + 1) * 64;
#pragma unroll
            for (int it = 0; it < 4; ++it)
                xp[it] = *(const bf16x8*)(Xb + (size_t)(m0 + it * 32 + srow) * EMBED + k1 + scol);
#pragma unroll
            for (int it = 0; it < NTN; ++it) {
                const int r = it * 32 + srow;
                if (MODE == 0) wpb[it] = *(const bf16x8*)(W + (size_t)(n0 + r) * EMBED + k1 + scol);
                else           wpf[it] = *(const f32x8*)(Wf + (size_t)(n0 + r) * EMBED + k1 + scol);
            }
        }
        barrier_nodrain();   // As/Bs writes visible to all waves
#pragma unroll
        for (int ks = 0; ks < 2; ++ks) {
            const int ko = (ks * 4 + quad) * 8;
            bf16x8 av[4], bv[NTN];
#pragma unroll
            for (int mt = 0; mt < 4; ++mt)
                av[mt] = *(const bf16x8*)(As + (wr + mt * 16 + l15) * 72 + ko);
#pragma unroll
            for (int nt = 0; nt < NTN; ++nt)
                bv[nt] = *(const bf16x8*)(Bs + (wc + nt * 16 + l15) * 72 + ko);
#pragma unroll
            for (int mt = 0; mt < 4; ++mt)
#pragma unroll
                for (int nt = 0; nt < NTN; ++nt)
                    acc[mt][nt] = mfma16(av[mt], bv[nt], acc[mt][nt]);
        }
    }

    // epilogue (C/D layout: col=l15, row=quad*4+i)
    float biasv[NTN];
#pragma unroll
    for (int nt = 0; nt < NTN; ++nt)
        biasv[nt] = Bi[n0 + wc + nt * 16 + l15];
#pragma unroll
    for (int mt = 0; mt < 4; ++mt) {
        const int mb = m0 + wr + mt * 16 + quad * 4;
        const int bb = mb >> 11, s0 = mb & (SEQ - 1);
#pragma unroll
        for (int nt = 0; nt < NTN; ++nt) {
            const int fc = n0 + wc + nt * 16 + l15;
            const int h = fc >> 6, d = fc & 63;
            float vv[4];
#pragma unroll
            for (int i = 0; i < 4; ++i) vv[i] = gelu_f(acc[mt][nt][i] + biasv[nt]);
            if (MODE == 1) {
#pragma unroll
                for (int i = 0; i < 4; ++i) Of[(size_t)(mb + i) * EMBED + fc] = vv[i];
            } else if (mat == 0) {
#pragma unroll
                for (int i = 0; i < 4; ++i)
                    O0[(((size_t)(bb * NH + h)) * SEQ + s0 + i) * HD + d] = (bf16_t)(vv[i] * SCQ);
            } else if (mat == 1) {
#pragma unroll
                for (int i = 0; i < 4; ++i)
                    O1[(((size_t)(bb * NH + h)) * SEQ + s0 + i) * HD + d] = (bf16_t)vv[i];
            } else {
                bf16x4 pk;
#pragma unroll
                for (int i = 0; i < 4; ++i) pk[i] = (bf16_t)vv[i];
                *(bf16x4*)(O2 + ((size_t)(bb * NH + h) * HD + d) * SEQ + s0) = pk;
            }
        }
    }
}

// ---------------------------------------------------------------------------
// Flash attention, S-transposed, scale-free softmax: p = exp2(s) directly.
//
// R5: P never touches LDS (T12). After swapped QK^T, lane l holds
// P[q=l15][key=quad*4+i+16jt]. PV's A-fragment needs P[q=l15][key=
// quad*8+e+32c]. Per c, pack jt-pair (2c,2c+1) with v_cvt_pk_bf16_f32,
// then ONE permlane32_swap + ONE permlane16_swap per word-pair:
//   (a0,a1,a2,a3),(b0,b1,b2,b3) -swap32-> (a0,a1,b0,b1),(a2,a3,b2,b3)
//                               -swap16-> (a0,a2,b0,b2),(a1,a3,b1,b3)
// which per dest-quad is exactly srcA/srcB of the fragment. 8 cvt_pk +
// 8 swaps (VALU) replace 4 ds_write_b64 + 2 ds_read_b128 + lgkm stall.
//
// Why: R0-R4 A/Bs established the kernel is LDS-ISSUE-BW bound at 4blk/CU
// (model: 288 LDS cyc/wave-tile ~ 88-98% of wall across R0/R1/R4).
// This cuts to 240 cyc/wave-tile and frees Ps (LDS 40960 -> 32768).
// KEPT: 16 q/wave, grid 32x32=1024=4/CU, nodrain barriers, 2-deep reg
// prefetch, XOR swizzle on K/V (conflicts 2.1M, verified).
// ---------------------------------------------------------------------------
#define FA_ITER(T, BUF, KR0, KR1, VR0, VR1)                                   \
    do {                                                                      \
        if ((T) + 1 < 32) {                                                   \
            bf16_t* Kn = Ks[(BUF) ^ 1];                                       \
            bf16_t* Vn = Vs[(BUF) ^ 1];                                       \
            *(bf16x8*)(Kn + sA)        = KR0;                                 \
            *(bf16x8*)(Kn + sA + 2048) = KR1;                                 \
            *(bf16x8*)(Vn + sA)        = VR0;                                 \
            *(bf16x8*)(Vn + sA + 2048) = VR1;                                 \
        }                                                                     \
        if ((T) + 3 < 32) {                                                   \
            const int kv = ((T) + 3) * 64;                                    \
            KR0 = *(const bf16x8*)(K + baseQK + (size_t)(kv + r0) * HD + c0); \
            KR1 = *(const bf16x8*)(K + baseQK + (size_t)(kv + r0 + 32) * HD + c0); \
            VR0 = *(const bf16x8*)(Vt + baseV + (size_t)r0 * SEQ + kv + c0);  \
            VR1 = *(const bf16x8*)(Vt + baseV + (size_t)(r0 + 32) * SEQ + kv + c0); \
        }                                                                     \
        const bf16_t* Kb = Ks[(BUF)];                                         \
        const bf16_t* Vb = Vs[(BUF)];                                         \
        f32x4 sf[4];                                                          \
        _Pragma("unroll")                                                     \
        for (int jt = 0; jt < 4; ++jt) sf[jt] = f32x4{0.f, 0.f, 0.f, 0.f};    \
        __builtin_amdgcn_s_setprio(1);                                        \
        _Pragma("unroll")                                                     \
        for (int ks = 0; ks < 2; ++ks) {                                      \
            const int ko = (ks * 32 + quad * 8) ^ cx;                         \
            _Pragma("unroll")                                                 \
            for (int jt = 0; jt < 4; ++jt) {                                  \
                const bf16x8 a = *(const bf16x8*)(Kb + ((jt * 16 + l15) << 6) + ko); \
                sf[jt] = mfma16(a, qf[ks], sf[jt]);                           \
            }                                                                 \
        }                                                                     \
        __builtin_amdgcn_s_setprio(0);                                        \
        u32 w0[4], w1[4];                                                     \
        _Pragma("unroll")                                                     \
        for (int jt = 0; jt < 4; ++jt) {                                      \
            _Pragma("unroll")                                                 \
            for (int i = 0; i < 4; ++i) sf[jt][i] = exp2f(sf[jt][i]);         \
            lacc += sf[jt];                                                   \
            w0[jt] = cvtpk_bf16(sf[jt][0], sf[jt][1]);                        \
            w1[jt] = cvtpk_bf16(sf[jt][2], sf[jt][3]);                        \
        }                                                                     \
        swap32(w0[0], w0[1]); swap16(w0[0], w0[1]);                           \
        swap32(w1[0], w1[1]); swap16(w1[0], w1[1]);                           \
        swap32(w0[2], w0[3]); swap16(w0[2], w0[3]);                           \
        swap32(w1[2], w1[3]); swap16(w1[2], w1[3]);                           \
        const u32x4 pq0 = u32x4{w0[0], w1[0], w0[1], w1[1]};                  \
        const u32x4 pq1 = u32x4{w0[2], w1[2], w0[3], w1[3]};                  \
        const bf16x8 pa0 = __builtin_bit_cast(bf16x8, pq0);                   \
        const bf16x8 pa1 = __builtin_bit_cast(bf16x8, pq1);                   \
        __builtin_amdgcn_s_setprio(1);                                        \
        _Pragma("unroll")                                                     \
        for (int c = 0; c < 2; ++c) {                                         \
            const int ko = (c * 32 + quad * 8) ^ cx;                          \
            const bf16x8 pa = c ? pa1 : pa0;                                  \
            _Pragma("unroll")                                                 \
            for (int nt = 0; nt < 4; ++nt) {                                  \
                const bf16x8 b = *(const bf16x8*)(Vb + ((nt * 16 + l15) << 6) + ko); \
                oacc[nt] = mfma16(pa, b, oacc[nt]);                           \
            }                                                                 \
        }                                                                     \
        __builtin_amdgcn_s_setprio(0);                                        \
        if ((T) < 31) barrier_nodrain();                                      \
    } while (0)

__global__ __launch_bounds__(256, 4)
void flash_attn_kernel(const bf16_t* __restrict__ Q,
                       const bf16_t* __restrict__ K,
                       const bf16_t* __restrict__ Vt,
                       bf16_t* __restrict__ Og)
{
    __shared__ __align__(16) bf16_t Ks[2][64 * 64];
    __shared__ __align__(16) bf16_t Vs[2][64 * 64];

    const int tid  = threadIdx.x;
    const int lane = tid & 63, w = tid >> 6, quad = lane >> 4, l15 = lane & 15;
    const int bh = blockIdx.y;
    const int q0 = blockIdx.x * 64;
    const size_t baseQK = (size_t)bh * SEQ * HD;
    const size_t baseV  = (size_t)bh * HD * SEQ;
    const int wm = w * 16;
    const int cx = (l15 & 7) << 3;   // compute-side swizzle: rows read are ==l15 (mod 8)

    // Q as B-operand fragments: n=qrow=l15, k=ks*32+quad*8
    bf16x8 qf[2];
#pragma unroll
    for (int ks = 0; ks < 2; ++ks)
        qf[ks] = *(const bf16x8*)(Q + baseQK + (size_t)(q0 + wm + l15) * HD + ks * 32 + quad * 8);

    f32x4 lacc = f32x4{0.f, 0.f, 0.f, 0.f};
    f32x4 oacc[4];
#pragma unroll
    for (int nt = 0; nt < 4; ++nt) oacc[nt] = f32x4{0.f, 0.f, 0.f, 0.f};

    const int r0 = tid >> 3, c0 = (tid & 7) * 8;
    // staging offset, swizzled; rows r0 and r0+32 share (row&7) -> +2048
    const int sA = (r0 << 6) + (c0 ^ ((r0 & 7) << 3));

    // reg sets: set B (idx 1) written at even t, set A (idx 0) at odd t.
    bf16x8 kA0, kA1, vA0, vA1;
    bf16x8 kB0, kB1, vB0, vB1;

    // prologue: T0 -> buf0 (via set A temp); T1 -> set B; T2 -> set A
    kA0 = *(const bf16x8*)(K + baseQK + (size_t)r0 * HD + c0);
    kA1 = *(const bf16x8*)(K + baseQK + (size_t)(r0 + 32) * HD + c0);
    vA0 = *(const bf16x8*)(Vt + baseV + (size_t)r0 * SEQ + c0);
    vA1 = *(const bf16x8*)(Vt + baseV + (size_t)(r0 + 32) * SEQ + c0);
    *(bf16x8*)(Ks[0] + sA)        = kA0;
    *(bf16x8*)(Ks[0] + sA + 2048) = kA1;
    *(bf16x8*)(Vs[0] + sA)        = vA0;
    *(bf16x8*)(Vs[0] + sA + 2048) = vA1;
    kB0 = *(const bf16x8*)(K + baseQK + (size_t)(64 + r0) * HD + c0);
    kB1 = *(const bf16x8*)(K + baseQK + (size_t)(64 + r0 + 32) * HD + c0);
    vB0 = *(const bf16x8*)(Vt + baseV + (size_t)r0 * SEQ + 64 + c0);
    vB1 = *(const bf16x8*)(Vt + baseV + (size_t)(r0 + 32) * SEQ + 64 + c0);
    kA0 = *(const bf16x8*)(K + baseQK + (size_t)(128 + r0) * HD + c0);
    kA1 = *(const bf16x8*)(K + baseQK + (size_t)(128 + r0 + 32) * HD + c0);
    vA0 = *(const bf16x8*)(Vt + baseV + (size_t)r0 * SEQ + 128 + c0);
    vA1 = *(const bf16x8*)(Vt + baseV + (size_t)(r0 + 32) * SEQ + 128 + c0);
    barrier_nodrain();

#pragma unroll 1
    for (int tt = 0; tt < 32; tt += 2) {
        FA_ITER(tt,     0, kB0, kB1, vB0, vB1);   // even t: buf0 compute, write set B
        FA_ITER(tt + 1, 1, kA0, kA1, vA0, vA1);   // odd t:  buf1 compute, write set A
    }

    // final l per qrow: reduce lane partials across quads, gather per C-row
    const int bidx = bh >> 3, h = bh & 7;
    float rs = (lacc[0] + lacc[1]) + (lacc[2] + lacc[3]);
    rs += __shfl_xor(rs, 16);
    rs += __shfl_xor(rs, 32);
    float lf[4];
#pragma unroll
    for (int i = 0; i < 4; ++i)
        lf[i] = __shfl(rs, (lane & 48) | (quad * 4 + i));
#pragma unroll
    for (int nt = 0; nt < 4; ++nt)
#pragma unroll
        for (int i = 0; i < 4; ++i) {
            const int s = q0 + wm + quad * 4 + i;
            const int d = nt * 16 + l15;
            Og[((size_t)(bidx * SEQ + s)) * EMBED + h * HD + d] =
                (bf16_t)(oacc[nt][i] / lf[i]);
        }
}

extern "C" void kernel_launch(void* const* d_in, const int* in_sizes, int n_in,
                              void* d_out, int out_size, void* d_ws, size_t ws_size,
                              hipStream_t stream)
{
    const float* x  = (const float*)d_in[0];
    const float* Wq = (const float*)d_in[1];
    const float* bq = (const float*)d_in[2];
    const float* Wk = (const float*)d_in[3];
    const float* bk = (const float*)d_in[4];
    const float* Wv = (const float*)d_in[5];
    const float* bv = (const float*)d_in[6];
    const float* Wo = (const float*)d_in[7];
    const float* bo = (const float*)d_in[8];
    float* out = (float*)d_out;

    const size_t NE = (size_t)MTOT * EMBED;   // 4,194,304 elems
    // Layout (ws use stays at proven 24 MB):
    //   d_out[0..NE)    : xb  (bf16 x)          -- dead after QKV GEMM
    //   d_out[NE..2NE)  : Qw  (bf16, pre-scaled)-- dead after flash
    //   ws[0..NE)       : Kw    ws[NE..2NE) : Vtw
    //   ws[2NE..3NE)    : Wb (1.5 MB, dead after QKV GEMM) then Ow (flash out)
    bf16_t* xb  = (bf16_t*)d_out;
    bf16_t* Qw  = (bf16_t*)d_out + NE;
    bf16_t* Kw  = (bf16_t*)d_ws;
    bf16_t* Vtw = Kw + NE;
    bf16_t* Ow  = Vtw + NE;
    bf16_t* Wb  = Ow;

    convert_kernel<<<dim3(64, 19), 256, 0, stream>>>(x, Wq, Wk, Wv, xb, Wb);
    gemm_gelu_kernel<0, 128><<<dim3(64, 12), 256, 0, stream>>>(
        xb, Wb, nullptr, bq, bk, bv, Qw, Kw, Vtw, nullptr);
    flash_attn_kernel<<<dim3(32, 32), 256, 0, stream>>>(Qw, Kw, Vtw, Ow);
    gemm_gelu_kernel<1, 64><<<dim3(64, 8), 256, 0, stream>>>(
        Ow, nullptr, Wo, bo, nullptr, nullptr, nullptr, nullptr, nullptr, out);
}